// Round 1
// baseline (646.647 us; speedup 1.0000x reference)
//
#include <hip/hip_runtime.h>
#include <hip/hip_bf16.h>

typedef __bf16  bf16x8  __attribute__((ext_vector_type(8)));
typedef float   f32x4   __attribute__((ext_vector_type(4)));
typedef unsigned short ushort8 __attribute__((ext_vector_type(8)));

#define D_MODEL 1024
#define HEAD_DIM 64
#define N_HEADS 16
#define BATCH 4
#define SEQ 2048
#define ROWS (BATCH*SEQ)   // 8192

// ---------------- fp32 -> bf16 convert (vectorized) ----------------
__global__ __launch_bounds__(256) void k_f32_to_bf16(const float* __restrict__ in,
                                                     __bf16* __restrict__ out, int n) {
  int i = (blockIdx.x * 256 + threadIdx.x) * 8;
  if (i >= n) return;
  float4 a = *(const float4*)(in + i);
  float4 b = *(const float4*)(in + i + 4);
  __bf16 r[8] __attribute__((aligned(16))) =
      {(__bf16)a.x,(__bf16)a.y,(__bf16)a.z,(__bf16)a.w,
       (__bf16)b.x,(__bf16)b.y,(__bf16)b.z,(__bf16)b.w};
  *(ushort8*)(out + i) = *(const ushort8*)r;
}

// ---------------- transpose + convert: in fp32 [R][C] -> out bf16 [C][R] ----------------
__global__ __launch_bounds__(256) void k_transpose_f32_bf16(const float* __restrict__ in,
                                                            __bf16* __restrict__ out,
                                                            int R, int C) {
  __shared__ float t[32][33];
  int tx = threadIdx.x & 31, ty = threadIdx.x >> 5;   // 32x8
  int r0 = blockIdx.y * 32, c0 = blockIdx.x * 32;
  #pragma unroll
  for (int i = 0; i < 4; ++i)
    t[ty + i*8][tx] = in[(size_t)(r0 + ty + i*8) * C + c0 + tx];
  __syncthreads();
  #pragma unroll
  for (int i = 0; i < 4; ++i)
    out[(size_t)(c0 + ty + i*8) * R + r0 + tx] = (__bf16)t[tx][ty + i*8];
}

// ---------------- bf16 MFMA GEMM: C[M][N] = A[M][K] * Bt[N][K]^T ----------------
// 128x128 tile, BK=32, 4 waves (2x2), wave tile 64x64 (4x4 of 16x16x32 MFMA)
template<typename OUT_T>
__global__ __launch_bounds__(256) void k_gemm(const __bf16* __restrict__ A,
                                              const __bf16* __restrict__ Bt,
                                              OUT_T* __restrict__ C,
                                              int M, int N, int K) {
  __shared__ __bf16 As[128][40] __attribute__((aligned(16)));   // pad 40 -> 2-way-free banks
  __shared__ __bf16 Bs[128][40] __attribute__((aligned(16)));
  const int tid  = threadIdx.x;
  const int lane = tid & 63, wave = tid >> 6;
  const int wm = wave >> 1, wn = wave & 1;
  const int l15 = lane & 15, lhi = lane >> 4;
  const int bm = blockIdx.x, bn = blockIdx.y;
  const int arow0 = bm * 128;
  const int brow0 = bn * 128;
  f32x4 acc[4][4] = {};
  const int sr = tid >> 2;        // 0..63
  const int sc = (tid & 3) * 8;   // 0,8,16,24

  for (int kt = 0; kt < K; kt += 32) {
    ushort8 a0 = *(const ushort8*)(A  + (size_t)(arow0 + sr     ) * K + kt + sc);
    ushort8 a1 = *(const ushort8*)(A  + (size_t)(arow0 + sr + 64) * K + kt + sc);
    ushort8 b0 = *(const ushort8*)(Bt + (size_t)(brow0 + sr     ) * K + kt + sc);
    ushort8 b1 = *(const ushort8*)(Bt + (size_t)(brow0 + sr + 64) * K + kt + sc);
    __syncthreads();             // protect previous iteration's frag reads
    *(ushort8*)&As[sr     ][sc] = a0;
    *(ushort8*)&As[sr + 64][sc] = a1;
    *(ushort8*)&Bs[sr     ][sc] = b0;
    *(ushort8*)&Bs[sr + 64][sc] = b1;
    __syncthreads();
    bf16x8 af[4], bfr[4];
    #pragma unroll
    for (int m = 0; m < 4; ++m)
      af[m] = *(const bf16x8*)&As[wm*64 + m*16 + l15][lhi*8];
    #pragma unroll
    for (int n = 0; n < 4; ++n)
      bfr[n] = *(const bf16x8*)&Bs[wn*64 + n*16 + l15][lhi*8];
    #pragma unroll
    for (int m = 0; m < 4; ++m)
      #pragma unroll
      for (int n = 0; n < 4; ++n)
        acc[m][n] = __builtin_amdgcn_mfma_f32_16x16x32_bf16(af[m], bfr[n], acc[m][n], 0, 0, 0);
  }
  // epilogue: D layout col=lane&15, row=(lane>>4)*4+reg  [HW-verified]
  #pragma unroll
  for (int m = 0; m < 4; ++m)
    #pragma unroll
    for (int n = 0; n < 4; ++n) {
      int row = arow0 + wm*64 + m*16 + lhi*4;
      int col = bn*128 + wn*64 + n*16 + l15;
      #pragma unroll
      for (int r = 0; r < 4; ++r)
        C[(size_t)(row + r) * N + col] = (OUT_T)acc[m][n][r];
    }
}

// ---------------- split KV -> Vt (transposed V) ----------------
// KV bf16 [8192][128] (cols 0..63 = K, 64..127 = V); Vt bf16 [B][64][SEQ]
__global__ __launch_bounds__(256) void k_vt_split(const __bf16* __restrict__ KV,
                                                  __bf16* __restrict__ Vt) {
  __shared__ __bf16 t[64][72] __attribute__((aligned(16)));
  int st = blockIdx.x, b = blockIdx.y;
  int tid = threadIdx.x;
  int rr = tid >> 3, cc = (tid & 7) * 8;
  #pragma unroll
  for (int i = 0; i < 2; ++i) {
    int s = rr + i*32;
    *(ushort8*)&t[s][cc] =
      *(const ushort8*)(KV + (size_t)(b*SEQ + st*64 + s) * 128 + 64 + cc);
  }
  __syncthreads();
  #pragma unroll
  for (int i = 0; i < 2; ++i) {
    int d = rr + i*32;
    __bf16 tmp[8] __attribute__((aligned(16)));
    #pragma unroll
    for (int j = 0; j < 8; ++j) tmp[j] = t[cc + j][d];
    *(ushort8*)(Vt + (size_t)(b*64 + d) * SEQ + st*64 + cc) = *(const ushort8*)tmp;
  }
}

// ---------------- flash attention (MQA) ----------------
// grid: (SEQ/64, N_HEADS, BATCH), 256 thr. Wave w owns q-rows [w*16, w*16+16).
__global__ __launch_bounds__(256) void k_attn(const __bf16* __restrict__ Q,   // [8192][1024]
                                              const __bf16* __restrict__ KV,  // [8192][128]
                                              const __bf16* __restrict__ Vt,  // [B][64][SEQ]
                                              __bf16* __restrict__ O) {       // [8192][1024]
  __shared__ __bf16 Qs[64][72] __attribute__((aligned(16)));
  __shared__ __bf16 Ps[64][72] __attribute__((aligned(16)));
  const int qt = blockIdx.x, h = blockIdx.y, b = blockIdx.z;
  const int tid = threadIdx.x, lane = tid & 63, wave = tid >> 6;
  const int l15 = lane & 15, lhi = lane >> 4;

  {  // stage Q tile (64 rows x 64 cols)
    int rr = tid >> 3, cc = (tid & 7) * 8;
    #pragma unroll
    for (int i = 0; i < 2; ++i) {
      int r = rr + i * 32;
      *(ushort8*)&Qs[r][cc] =
        *(const ushort8*)(Q + (size_t)(b*SEQ + qt*64 + r) * D_MODEL + h*HEAD_DIM + cc);
    }
  }
  __syncthreads();
  bf16x8 aq0 = *(const bf16x8*)&Qs[wave*16 + l15][     lhi*8];
  bf16x8 aq1 = *(const bf16x8*)&Qs[wave*16 + l15][32 + lhi*8];

  f32x4 oacc[4] = {};
  float mrun[4], lrun[4];
  #pragma unroll
  for (int r = 0; r < 4; ++r) { mrun[r] = -__builtin_inff(); lrun[r] = 0.f; }

  const __bf16* Kb = KV + (size_t)b * SEQ * 128;
  const __bf16* Vb = Vt + (size_t)b * 64 * SEQ;

  for (int kt = 0; kt < SEQ/64; ++kt) {
    // ---- scores S[16q][64k] ----
    f32x4 s[4] = {};
    #pragma unroll
    for (int n = 0; n < 4; ++n) {
      const __bf16* kp = Kb + (size_t)(kt*64 + n*16 + l15) * 128;
      bf16x8 kb0 = *(const bf16x8*)(kp +      lhi*8);
      bf16x8 kb1 = *(const bf16x8*)(kp + 32 + lhi*8);
      s[n] = __builtin_amdgcn_mfma_f32_16x16x32_bf16(aq0, kb0, s[n], 0, 0, 0);
      s[n] = __builtin_amdgcn_mfma_f32_16x16x32_bf16(aq1, kb1, s[n], 0, 0, 0);
    }
    // ---- scale + row max (16-lane group shuffle reduce) ----
    float tm[4];
    #pragma unroll
    for (int r = 0; r < 4; ++r) {
      s[0][r] *= 0.125f; s[1][r] *= 0.125f; s[2][r] *= 0.125f; s[3][r] *= 0.125f;
      tm[r] = fmaxf(fmaxf(s[0][r], s[1][r]), fmaxf(s[2][r], s[3][r]));
    }
    #pragma unroll
    for (int off = 1; off < 16; off <<= 1)
      #pragma unroll
      for (int r = 0; r < 4; ++r)
        tm[r] = fmaxf(tm[r], __shfl_xor(tm[r], off, 64));
    // ---- online softmax update ----
    float corr[4];
    #pragma unroll
    for (int r = 0; r < 4; ++r) {
      float mnew = fmaxf(mrun[r], tm[r]);
      corr[r] = __expf(mrun[r] - mnew);
      mrun[r] = mnew;
      lrun[r] *= corr[r];
    }
    #pragma unroll
    for (int n = 0; n < 4; ++n)
      #pragma unroll
      for (int r = 0; r < 4; ++r)
        oacc[n][r] *= corr[r];
    // ---- P = exp(s-m) -> LDS (wave-private rows) ----
    #pragma unroll
    for (int n = 0; n < 4; ++n)
      #pragma unroll
      for (int r = 0; r < 4; ++r) {
        float p = __expf(s[n][r] - mrun[r]);
        lrun[r] += p;
        Ps[wave*16 + lhi*4 + r][n*16 + l15] = (__bf16)p;
      }
    __syncthreads();
    // ---- PV ----
    bf16x8 ap0 = *(const bf16x8*)&Ps[wave*16 + l15][     lhi*8];
    bf16x8 ap1 = *(const bf16x8*)&Ps[wave*16 + l15][32 + lhi*8];
    #pragma unroll
    for (int n = 0; n < 4; ++n) {
      const __bf16* vp = Vb + (size_t)(n*16 + l15) * SEQ + kt*64;
      bf16x8 v0 = *(const bf16x8*)(vp +      lhi*8);
      bf16x8 v1 = *(const bf16x8*)(vp + 32 + lhi*8);
      oacc[n] = __builtin_amdgcn_mfma_f32_16x16x32_bf16(ap0, v0, oacc[n], 0, 0, 0);
      oacc[n] = __builtin_amdgcn_mfma_f32_16x16x32_bf16(ap1, v1, oacc[n], 0, 0, 0);
    }
    __syncthreads();
  }
  // ---- final row sums + write ----
  #pragma unroll
  for (int off = 1; off < 16; off <<= 1)
    #pragma unroll
    for (int r = 0; r < 4; ++r)
      lrun[r] += __shfl_xor(lrun[r], off, 64);
  #pragma unroll
  for (int n = 0; n < 4; ++n)
    #pragma unroll
    for (int r = 0; r < 4; ++r) {
      size_t row = (size_t)b*SEQ + qt*64 + wave*16 + lhi*4 + r;
      O[row * D_MODEL + h*HEAD_DIM + n*16 + l15] = (__bf16)(oacc[n][r] / lrun[r]);
    }
}

extern "C" void kernel_launch(void* const* d_in, const int* in_sizes, int n_in,
                              void* d_out, int out_size, void* d_ws, size_t ws_size,
                              hipStream_t stream) {
  const float* x  = (const float*)d_in[0];
  const float* Wq = (const float*)d_in[1];
  const float* Wk = (const float*)d_in[2];
  const float* Wv = (const float*)d_in[3];
  const float* Wo = (const float*)d_in[4];
  float* out = (float*)d_out;

  char* ws = (char*)d_ws;
  size_t off = 0;
  auto alloc = [&](size_t bytes) -> void* {
    void* p = ws + off;
    off += (bytes + 255) & ~(size_t)255;
    return p;
  };
  __bf16* xb   = (__bf16*)alloc((size_t)ROWS * D_MODEL * 2);   // also reused as attn_out
  __bf16* Qb   = (__bf16*)alloc((size_t)ROWS * D_MODEL * 2);
  __bf16* WqT  = (__bf16*)alloc((size_t)D_MODEL * D_MODEL * 2);
  __bf16* WkvT = (__bf16*)alloc((size_t)128 * D_MODEL * 2);
  __bf16* WoT  = (__bf16*)alloc((size_t)D_MODEL * D_MODEL * 2);
  __bf16* KVb  = (__bf16*)alloc((size_t)ROWS * 128 * 2);
  __bf16* Vtb  = (__bf16*)alloc((size_t)BATCH * 64 * SEQ * 2);

  k_f32_to_bf16<<<ROWS*D_MODEL/2048, 256, 0, stream>>>(x, xb, ROWS*D_MODEL);
  k_transpose_f32_bf16<<<dim3(D_MODEL/32, D_MODEL/32), 256, 0, stream>>>(Wq, WqT, D_MODEL, D_MODEL);
  k_transpose_f32_bf16<<<dim3(HEAD_DIM/32, D_MODEL/32), 256, 0, stream>>>(Wk, WkvT, D_MODEL, HEAD_DIM);
  k_transpose_f32_bf16<<<dim3(HEAD_DIM/32, D_MODEL/32), 256, 0, stream>>>(Wv, WkvT + 64*D_MODEL, D_MODEL, HEAD_DIM);
  k_transpose_f32_bf16<<<dim3(D_MODEL/32, D_MODEL/32), 256, 0, stream>>>(Wo, WoT, D_MODEL, D_MODEL);

  k_gemm<__bf16><<<dim3(ROWS/128, D_MODEL/128), 256, 0, stream>>>(xb, WqT, Qb, ROWS, D_MODEL, D_MODEL);
  k_gemm<__bf16><<<dim3(ROWS/128, 1),           256, 0, stream>>>(xb, WkvT, KVb, ROWS, 128, D_MODEL);
  k_vt_split<<<dim3(SEQ/64, BATCH), 256, 0, stream>>>(KVb, Vtb);
  k_attn<<<dim3(SEQ/64, N_HEADS, BATCH), 256, 0, stream>>>(Qb, KVb, Vtb, xb);
  k_gemm<float><<<dim3(ROWS/128, D_MODEL/128), 256, 0, stream>>>(xb, WoT, out, ROWS, D_MODEL, D_MODEL);
}

// Round 4
// 619.598 us; speedup vs baseline: 1.0437x; 1.0437x over previous
//
#include <hip/hip_runtime.h>
#include <hip/hip_bf16.h>

typedef __bf16  bf16x8  __attribute__((ext_vector_type(8)));
typedef float   f32x4   __attribute__((ext_vector_type(4)));
typedef unsigned short ushort8 __attribute__((ext_vector_type(8)));

#define D_MODEL 1024
#define HEAD_DIM 64
#define N_HEADS 16
#define BATCH 4
#define SEQ 2048
#define ROWS (BATCH*SEQ)   // 8192
#define QKV_LD 1152        // 1024 (Q) + 64 (K) + 64 (V)

#define AS1 __attribute__((address_space(1)))
#define AS3 __attribute__((address_space(3)))

// ---------------- fp32 -> bf16 convert (vectorized) ----------------
__global__ __launch_bounds__(256) void k_f32_to_bf16(const float* __restrict__ in,
                                                     __bf16* __restrict__ out, int n) {
  int i = (blockIdx.x * 256 + threadIdx.x) * 8;
  if (i >= n) return;
  float4 a = *(const float4*)(in + i);
  float4 b = *(const float4*)(in + i + 4);
  __bf16 r[8] __attribute__((aligned(16))) =
      {(__bf16)a.x,(__bf16)a.y,(__bf16)a.z,(__bf16)a.w,
       (__bf16)b.x,(__bf16)b.y,(__bf16)b.z,(__bf16)b.w};
  *(ushort8*)(out + i) = *(const ushort8*)r;
}

// ---------------- transpose + convert: in fp32 [R][C] -> out bf16 [C][R] ----------------
__global__ __launch_bounds__(256) void k_transpose_f32_bf16(const float* __restrict__ in,
                                                            __bf16* __restrict__ out,
                                                            int R, int C) {
  __shared__ float t[32][33];
  int tx = threadIdx.x & 31, ty = threadIdx.x >> 5;   // 32x8
  int r0 = blockIdx.y * 32, c0 = blockIdx.x * 32;
  #pragma unroll
  for (int i = 0; i < 4; ++i)
    t[ty + i*8][tx] = in[(size_t)(r0 + ty + i*8) * C + c0 + tx];
  __syncthreads();
  #pragma unroll
  for (int i = 0; i < 4; ++i)
    out[(size_t)(c0 + ty + i*8) * R + r0 + tx] = (__bf16)t[tx][ty + i*8];
}

// ---------------- bf16 MFMA GEMM: C[M][N] = A[M][K] * Bt[N][K]^T ----------------
// 128x128 tile, BK=32, 4 waves (2x2), wave tile 64x64, global_load_lds staging (m97 structure)
template<typename OUT_T>
__global__ __launch_bounds__(256) void k_gemm(const __bf16* __restrict__ A,
                                              const __bf16* __restrict__ Bt,
                                              OUT_T* __restrict__ C,
                                              int M, int N, int K) {
  __shared__ __bf16 As[128*32] __attribute__((aligned(16)));   // linear (global_load_lds dest)
  __shared__ __bf16 Bs[128*32] __attribute__((aligned(16)));
  const int tid  = threadIdx.x;
  const int lane = tid & 63, wave = tid >> 6;
  const int wm = wave >> 1, wn = wave & 1;
  const int l15 = lane & 15, lhi = lane >> 4;
  const int arow0 = blockIdx.x * 128;
  const int brow0 = blockIdx.y * 128;
  f32x4 acc[4][4] = {};
  const int srow = lane >> 2;        // 0..15
  const int scol = (lane & 3) * 8;   // 0,8,16,24

  for (int kt = 0; kt < K; kt += 32) {
    __syncthreads();   // previous iteration's frag reads done before overwrite
    #pragma unroll
    for (int i = 0; i < 2; ++i) {
      int chunk = i*4 + wave;              // 0..7, 16 rows each
      int r = chunk*16 + srow;
      __builtin_amdgcn_global_load_lds(
          (const AS1 unsigned int*)(A  + (size_t)(arow0 + r)*K + kt + scol),
          (AS3 unsigned int*)(As + chunk*512), 16, 0, 0);
      __builtin_amdgcn_global_load_lds(
          (const AS1 unsigned int*)(Bt + (size_t)(brow0 + r)*K + kt + scol),
          (AS3 unsigned int*)(Bs + chunk*512), 16, 0, 0);
    }
    __syncthreads();   // drains vmcnt (compiler emits vmcnt(0) before s_barrier)
    bf16x8 af[4], bfr[4];
    #pragma unroll
    for (int m = 0; m < 4; ++m)
      af[m] = *(const bf16x8*)(As + (wm*64 + m*16 + l15)*32 + lhi*8);
    #pragma unroll
    for (int n = 0; n < 4; ++n)
      bfr[n] = *(const bf16x8*)(Bs + (wn*64 + n*16 + l15)*32 + lhi*8);
    #pragma unroll
    for (int m = 0; m < 4; ++m)
      #pragma unroll
      for (int n = 0; n < 4; ++n)
        acc[m][n] = __builtin_amdgcn_mfma_f32_16x16x32_bf16(af[m], bfr[n], acc[m][n], 0, 0, 0);
  }
  // epilogue: D layout col=lane&15, row=(lane>>4)*4+reg  [HW-verified]
  #pragma unroll
  for (int m = 0; m < 4; ++m)
    #pragma unroll
    for (int n = 0; n < 4; ++n) {
      int row = arow0 + wm*64 + m*16 + lhi*4;
      int col = brow0 + wn*64 + n*16 + l15;
      #pragma unroll
      for (int r = 0; r < 4; ++r)
        C[(size_t)(row + r) * N + col] = (OUT_T)acc[m][n][r];
    }
}

// ---------------- split V cols of QKV -> Vt (transposed V) ----------------
// QKV bf16 [8192][1152] (cols 1088..1151 = V); Vt bf16 [B][64][SEQ]
__global__ __launch_bounds__(256) void k_vt_split(const __bf16* __restrict__ QKV,
                                                  __bf16* __restrict__ Vt) {
  __shared__ __bf16 t[64][72] __attribute__((aligned(16)));
  int st = blockIdx.x, b = blockIdx.y;
  int tid = threadIdx.x;
  int rr = tid >> 3, cc = (tid & 7) * 8;
  #pragma unroll
  for (int i = 0; i < 2; ++i) {
    int s = rr + i*32;
    *(ushort8*)&t[s][cc] =
      *(const ushort8*)(QKV + (size_t)(b*SEQ + st*64 + s) * QKV_LD + 1088 + cc);
  }
  __syncthreads();
  #pragma unroll
  for (int i = 0; i < 2; ++i) {
    int d = rr + i*32;
    __bf16 tmp[8] __attribute__((aligned(16)));
    #pragma unroll
    for (int j = 0; j < 8; ++j) tmp[j] = t[cc + j][d];
    *(ushort8*)(Vt + (size_t)(b*64 + d) * SEQ + st*64 + cc) = *(const ushort8*)tmp;
  }
}

// ---------------- flash attention (MQA), barrier-free ----------------
// grid: (SEQ/64, N_HEADS, BATCH), 256 thr. Wave w owns q-rows [w*16, w*16+16).
// Q, K read straight from QKV buffer (L2-resident); P via wave-private LDS.
__global__ __launch_bounds__(256) void k_attn(const __bf16* __restrict__ QKV, // [8192][1152]
                                              const __bf16* __restrict__ Vt,  // [B][64][SEQ]
                                              __bf16* __restrict__ O) {       // [8192][1024]
  __shared__ __bf16 Ps[4][16][72] __attribute__((aligned(16)));   // per-wave P tile
  const int qt = blockIdx.x, h = blockIdx.y, b = blockIdx.z;
  const int tid = threadIdx.x, lane = tid & 63, wave = tid >> 6;
  const int l15 = lane & 15, lhi = lane >> 4;

  // Q fragments: direct global loads (no LDS, no barrier)
  const __bf16* qp = QKV + (size_t)(b*SEQ + qt*64 + wave*16 + l15) * QKV_LD + h*HEAD_DIM;
  bf16x8 aq0 = *(const bf16x8*)(qp +      lhi*8);
  bf16x8 aq1 = *(const bf16x8*)(qp + 32 + lhi*8);

  f32x4 oacc[4] = {};
  float mrun[4], lrun[4];
  #pragma unroll
  for (int r = 0; r < 4; ++r) { mrun[r] = -__builtin_inff(); lrun[r] = 0.f; }

  const __bf16* Kb = QKV + (size_t)b * SEQ * QKV_LD + 1024;   // K cols
  const __bf16* Vb = Vt + (size_t)b * 64 * SEQ;

  for (int kt = 0; kt < SEQ/64; ++kt) {
    // ---- scores S[16q][64k] ----
    f32x4 s[4] = {};
    __builtin_amdgcn_s_setprio(1);
    #pragma unroll
    for (int n = 0; n < 4; ++n) {
      const __bf16* kp = Kb + (size_t)(kt*64 + n*16 + l15) * QKV_LD;
      bf16x8 kb0 = *(const bf16x8*)(kp +      lhi*8);
      bf16x8 kb1 = *(const bf16x8*)(kp + 32 + lhi*8);
      s[n] = __builtin_amdgcn_mfma_f32_16x16x32_bf16(aq0, kb0, s[n], 0, 0, 0);
      s[n] = __builtin_amdgcn_mfma_f32_16x16x32_bf16(aq1, kb1, s[n], 0, 0, 0);
    }
    __builtin_amdgcn_s_setprio(0);
    // ---- row max over 64 keys (16-lane group shuffle reduce on raw scores) ----
    float tm[4];
    #pragma unroll
    for (int r = 0; r < 4; ++r)
      tm[r] = fmaxf(fmaxf(s[0][r], s[1][r]), fmaxf(s[2][r], s[3][r]));
    #pragma unroll
    for (int off = 1; off < 16; off <<= 1)
      #pragma unroll
      for (int r = 0; r < 4; ++r)
        tm[r] = fmaxf(tm[r], __shfl_xor(tm[r], off, 64));
    // ---- online softmax update (1/8 scale folded into exp) ----
    float corr[4];
    #pragma unroll
    for (int r = 0; r < 4; ++r) {
      float mnew = fmaxf(mrun[r], tm[r]);
      corr[r] = __expf((mrun[r] - mnew) * 0.125f);
      mrun[r] = mnew;
      lrun[r] *= corr[r];
    }
    #pragma unroll
    for (int n = 0; n < 4; ++n)
      #pragma unroll
      for (int r = 0; r < 4; ++r)
        oacc[n][r] *= corr[r];
    // ---- P = exp((s-m)/8) -> wave-private LDS (no barrier needed) ----
    #pragma unroll
    for (int n = 0; n < 4; ++n)
      #pragma unroll
      for (int r = 0; r < 4; ++r) {
        float p = __expf((s[n][r] - mrun[r]) * 0.125f);
        lrun[r] += p;
        Ps[wave][lhi*4 + r][n*16 + l15] = (__bf16)p;
      }
    // ---- PV (in-wave ds ordering handles the P write->read dependency) ----
    bf16x8 ap0 = *(const bf16x8*)&Ps[wave][l15][     lhi*8];
    bf16x8 ap1 = *(const bf16x8*)&Ps[wave][l15][32 + lhi*8];
    __builtin_amdgcn_s_setprio(1);
    #pragma unroll
    for (int n = 0; n < 4; ++n) {
      const __bf16* vp = Vb + (size_t)(n*16 + l15) * SEQ + kt*64;
      bf16x8 v0 = *(const bf16x8*)(vp +      lhi*8);
      bf16x8 v1 = *(const bf16x8*)(vp + 32 + lhi*8);
      oacc[n] = __builtin_amdgcn_mfma_f32_16x16x32_bf16(ap0, v0, oacc[n], 0, 0, 0);
      oacc[n] = __builtin_amdgcn_mfma_f32_16x16x32_bf16(ap1, v1, oacc[n], 0, 0, 0);
    }
    __builtin_amdgcn_s_setprio(0);
  }
  // ---- final row sums + write ----
  #pragma unroll
  for (int off = 1; off < 16; off <<= 1)
    #pragma unroll
    for (int r = 0; r < 4; ++r)
      lrun[r] += __shfl_xor(lrun[r], off, 64);
  float rinv[4];
  #pragma unroll
  for (int r = 0; r < 4; ++r) rinv[r] = __builtin_amdgcn_rcpf(lrun[r]);
  #pragma unroll
  for (int n = 0; n < 4; ++n)
    #pragma unroll
    for (int r = 0; r < 4; ++r) {
      size_t row = (size_t)b*SEQ + qt*64 + wave*16 + lhi*4 + r;
      O[row * D_MODEL + h*HEAD_DIM + n*16 + l15] = (__bf16)(oacc[n][r] * rinv[r]);
    }
}

extern "C" void kernel_launch(void* const* d_in, const int* in_sizes, int n_in,
                              void* d_out, int out_size, void* d_ws, size_t ws_size,
                              hipStream_t stream) {
  const float* x  = (const float*)d_in[0];
  const float* Wq = (const float*)d_in[1];
  const float* Wk = (const float*)d_in[2];
  const float* Wv = (const float*)d_in[3];
  const float* Wo = (const float*)d_in[4];
  float* out = (float*)d_out;

  char* ws = (char*)d_ws;
  size_t off = 0;
  auto alloc = [&](size_t bytes) -> void* {
    void* p = ws + off;
    off += (bytes + 255) & ~(size_t)255;
    return p;
  };
  __bf16* xb    = (__bf16*)alloc((size_t)ROWS * D_MODEL * 2);   // x bf16; reused as attn out
  __bf16* QKVb  = (__bf16*)alloc((size_t)ROWS * QKV_LD * 2);
  __bf16* WqkvT = (__bf16*)alloc((size_t)QKV_LD * D_MODEL * 2); // rows: 0..1023 Wq, 1024..1087 Wk, 1088..1151 Wv
  __bf16* WoT   = (__bf16*)alloc((size_t)D_MODEL * D_MODEL * 2);
  __bf16* Vtb   = (__bf16*)alloc((size_t)BATCH * 64 * SEQ * 2);

  k_f32_to_bf16<<<ROWS*D_MODEL/2048, 256, 0, stream>>>(x, xb, ROWS*D_MODEL);
  k_transpose_f32_bf16<<<dim3(D_MODEL/32, D_MODEL/32), 256, 0, stream>>>(Wq, WqkvT, D_MODEL, D_MODEL);
  k_transpose_f32_bf16<<<dim3(HEAD_DIM/32, D_MODEL/32), 256, 0, stream>>>(Wk, WqkvT + (size_t)1024*D_MODEL, D_MODEL, HEAD_DIM);
  k_transpose_f32_bf16<<<dim3(HEAD_DIM/32, D_MODEL/32), 256, 0, stream>>>(Wv, WqkvT + (size_t)1088*D_MODEL, D_MODEL, HEAD_DIM);
  k_transpose_f32_bf16<<<dim3(D_MODEL/32, D_MODEL/32), 256, 0, stream>>>(Wo, WoT, D_MODEL, D_MODEL);

  // fused QKV projection: [8192,1024] x [1024,1152] -> [8192,1152]
  k_gemm<__bf16><<<dim3(ROWS/128, QKV_LD/128), 256, 0, stream>>>(xb, WqkvT, QKVb, ROWS, QKV_LD, D_MODEL);
  k_vt_split<<<dim3(SEQ/64, BATCH), 256, 0, stream>>>(QKVb, Vtb);
  k_attn<<<dim3(SEQ/64, N_HEADS, BATCH), 256, 0, stream>>>(QKVb, Vtb, xb);
  // output projection
  k_gemm<float><<<dim3(ROWS/128, D_MODEL/128), 256, 0, stream>>>(xb, WoT, out, ROWS, D_MODEL, D_MODEL);
}

// Round 5
// 323.333 us; speedup vs baseline: 1.9999x; 1.9163x over previous
//
#include <hip/hip_runtime.h>
#include <hip/hip_bf16.h>

typedef __bf16  bf16x8  __attribute__((ext_vector_type(8)));
typedef __bf16  bf16x4  __attribute__((ext_vector_type(4)));
typedef float   f32x4   __attribute__((ext_vector_type(4)));
typedef unsigned short ushort8 __attribute__((ext_vector_type(8)));

#define D_MODEL 1024
#define HEAD_DIM 64
#define N_HEADS 16
#define BATCH 4
#define SEQ 2048
#define ROWS (BATCH*SEQ)   // 8192
#define QKV_LD 1152        // 1024 (Q) + 64 (K) + 64 (V)
#define VT_LD 2080         // padded: 4160 B rows, breaks 4KB channel aliasing

#define AS1 __attribute__((address_space(1)))
#define AS3 __attribute__((address_space(3)))

// ---------------- fp32 -> bf16 convert (vectorized) ----------------
__global__ __launch_bounds__(256) void k_f32_to_bf16(const float* __restrict__ in,
                                                     __bf16* __restrict__ out, int n) {
  int i = (blockIdx.x * 256 + threadIdx.x) * 8;
  if (i >= n) return;
  float4 a = *(const float4*)(in + i);
  float4 b = *(const float4*)(in + i + 4);
  __bf16 r[8] __attribute__((aligned(16))) =
      {(__bf16)a.x,(__bf16)a.y,(__bf16)a.z,(__bf16)a.w,
       (__bf16)b.x,(__bf16)b.y,(__bf16)b.z,(__bf16)b.w};
  *(ushort8*)(out + i) = *(const ushort8*)r;
}

// ---------------- transpose + convert: in fp32 [R][C] -> out bf16 [C][R'] ----------------
__global__ __launch_bounds__(256) void k_transpose_f32_bf16(const float* __restrict__ in,
                                                            __bf16* __restrict__ out,
                                                            int R, int C) {
  __shared__ float t[32][33];
  int tx = threadIdx.x & 31, ty = threadIdx.x >> 5;   // 32x8
  int r0 = blockIdx.y * 32, c0 = blockIdx.x * 32;
  #pragma unroll
  for (int i = 0; i < 4; ++i)
    t[ty + i*8][tx] = in[(size_t)(r0 + ty + i*8) * C + c0 + tx];
  __syncthreads();
  #pragma unroll
  for (int i = 0; i < 4; ++i)
    out[(size_t)(c0 + ty + i*8) * R + r0 + tx] = (__bf16)t[tx][ty + i*8];
}

// ---------------- bf16 MFMA GEMM: C[M][N] = A[M][K] * Bt[N][K]^T ----------------
template<typename OUT_T>
__global__ __launch_bounds__(256) void k_gemm(const __bf16* __restrict__ A,
                                              const __bf16* __restrict__ Bt,
                                              OUT_T* __restrict__ C,
                                              int M, int N, int K) {
  __shared__ __bf16 As[128*32] __attribute__((aligned(16)));
  __shared__ __bf16 Bs[128*32] __attribute__((aligned(16)));
  const int tid  = threadIdx.x;
  const int lane = tid & 63, wave = tid >> 6;
  const int wm = wave >> 1, wn = wave & 1;
  const int l15 = lane & 15, lhi = lane >> 4;
  const int arow0 = blockIdx.x * 128;
  const int brow0 = blockIdx.y * 128;
  f32x4 acc[4][4] = {};
  const int srow = lane >> 2;        // 0..15
  const int scol = (lane & 3) * 8;   // 0,8,16,24

  for (int kt = 0; kt < K; kt += 32) {
    __syncthreads();
    #pragma unroll
    for (int i = 0; i < 2; ++i) {
      int chunk = i*4 + wave;
      int r = chunk*16 + srow;
      __builtin_amdgcn_global_load_lds(
          (const AS1 unsigned int*)(A  + (size_t)(arow0 + r)*K + kt + scol),
          (AS3 unsigned int*)(As + chunk*512), 16, 0, 0);
      __builtin_amdgcn_global_load_lds(
          (const AS1 unsigned int*)(Bt + (size_t)(brow0 + r)*K + kt + scol),
          (AS3 unsigned int*)(Bs + chunk*512), 16, 0, 0);
    }
    __syncthreads();
    bf16x8 af[4], bfr[4];
    #pragma unroll
    for (int m = 0; m < 4; ++m)
      af[m] = *(const bf16x8*)(As + (wm*64 + m*16 + l15)*32 + lhi*8);
    #pragma unroll
    for (int n = 0; n < 4; ++n)
      bfr[n] = *(const bf16x8*)(Bs + (wn*64 + n*16 + l15)*32 + lhi*8);
    #pragma unroll
    for (int m = 0; m < 4; ++m)
      #pragma unroll
      for (int n = 0; n < 4; ++n)
        acc[m][n] = __builtin_amdgcn_mfma_f32_16x16x32_bf16(af[m], bfr[n], acc[m][n], 0, 0, 0);
  }
  #pragma unroll
  for (int m = 0; m < 4; ++m)
    #pragma unroll
    for (int n = 0; n < 4; ++n) {
      int row = arow0 + wm*64 + m*16 + lhi*4;
      int col = brow0 + wn*64 + n*16 + l15;
      #pragma unroll
      for (int r = 0; r < 4; ++r)
        C[(size_t)(row + r) * N + col] = (OUT_T)acc[m][n][r];
    }
}

// ---------------- split V cols of QKV -> Vt (transposed V, padded stride) ----------------
__global__ __launch_bounds__(256) void k_vt_split(const __bf16* __restrict__ QKV,
                                                  __bf16* __restrict__ Vt) {
  __shared__ __bf16 t[64][72] __attribute__((aligned(16)));
  int st = blockIdx.x, b = blockIdx.y;
  int tid = threadIdx.x;
  int rr = tid >> 3, cc = (tid & 7) * 8;
  #pragma unroll
  for (int i = 0; i < 2; ++i) {
    int s = rr + i*32;
    *(ushort8*)&t[s][cc] =
      *(const ushort8*)(QKV + (size_t)(b*SEQ + st*64 + s) * QKV_LD + 1088 + cc);
  }
  __syncthreads();
  #pragma unroll
  for (int i = 0; i < 2; ++i) {
    int d = rr + i*32;
    __bf16 tmp[8] __attribute__((aligned(16)));
    #pragma unroll
    for (int j = 0; j < 8; ++j) tmp[j] = t[cc + j][d];
    *(ushort8*)(Vt + (size_t)(b*64 + d) * VT_LD + st*64 + cc) = *(const ushort8*)tmp;
  }
}

// ---------------- flash attention (MQA), 8-wave, LDS-staged K/V, dbuf + counted vmcnt ----
// grid: (SEQ/256, N_HEADS, BATCH), 512 thr. Wave w owns q-rows [w*32, w*32+32).
// K_lds[key][dim] XOR-swz by (key>>3); V_lds[d][key] XOR-swz by (d&7); P XOR-swz by (row&7).
// QK B-frag key remap: lane l15, block n -> key = l15*4+n  => P row-write is one b64 store.
__global__ __launch_bounds__(512) void k_attn(const __bf16* __restrict__ QKV, // [8192][1152]
                                              const __bf16* __restrict__ Vt,  // [B][64][VT_LD]
                                              __bf16* __restrict__ O) {       // [8192][1024]
  __shared__ __bf16 Kl[2][64*64];   // 8KB per buf, linear dest for global_load_lds
  __shared__ __bf16 Vl[2][64*64];
  __shared__ __bf16 Pl[8][32*64];   // per-wave P tile (32 q-rows x 64 keys)
  const int qt = blockIdx.x, h = blockIdx.y, b = blockIdx.z;
  const int tid = threadIdx.x, lane = tid & 63, w = tid >> 6;
  const int l15 = lane & 15, lhi = lane >> 4;

  // staging geometry: wave w covers rows w*8..w*8+7 of the 64-row tile, 8 lanes/row
  const int srow = lane >> 3;              // 0..7
  const int j8   = lane & 7;               // dim/key block within row
  const int key_t = w*8 + srow;            // tile row this lane stages (key for K, d for V)
  const int jk = j8 ^ (w & 7);             // inverse-swizzled K source block ((key>>3)&7 == w)
  const int jv = j8 ^ srow;                // inverse-swizzled V source block ((d&7) == srow)
  const __bf16* Kg = QKV + (size_t)b*SEQ*QKV_LD + 1024;
  const __bf16* Vg = Vt  + (size_t)b*64*VT_LD;

  auto stage = [&](int t, int buf) {
    __builtin_amdgcn_global_load_lds(
        (const AS1 unsigned int*)(Kg + (size_t)(t*64 + key_t)*QKV_LD + jk*8),
        (AS3 unsigned int*)(&Kl[buf][0] + w*512), 16, 0, 0);
    __builtin_amdgcn_global_load_lds(
        (const AS1 unsigned int*)(Vg + (size_t)key_t*VT_LD + t*64 + jv*8),
        (AS3 unsigned int*)(&Vl[buf][0] + w*512), 16, 0, 0);
  };

  stage(0, 0);

  // Q fragments (2 m-tiles x 2 k-halves), direct global
  bf16x8 aq[2][2];
  {
    const __bf16* qp = QKV + (size_t)(b*SEQ + qt*256 + w*32 + l15)*QKV_LD + h*HEAD_DIM;
    aq[0][0] = *(const bf16x8*)(qp +               lhi*8);
    aq[0][1] = *(const bf16x8*)(qp +          32 + lhi*8);
    aq[1][0] = *(const bf16x8*)(qp + 16*QKV_LD +      lhi*8);
    aq[1][1] = *(const bf16x8*)(qp + 16*QKV_LD + 32 + lhi*8);
  }

  f32x4 oacc[2][4] = {};
  float mrun[2][4], lrun[2][4];
  #pragma unroll
  for (int m = 0; m < 2; ++m)
    #pragma unroll
    for (int r = 0; r < 4; ++r) { mrun[m][r] = -__builtin_inff(); lrun[m][r] = 0.f; }

  asm volatile("s_waitcnt vmcnt(0)" ::: "memory");
  __builtin_amdgcn_s_barrier();

  for (int t = 0; t < SEQ/64; ++t) {
    const int cur = t & 1;
    if (t < SEQ/64 - 1) {
      stage(t+1, cur^1);                                   // prefetch stays in flight
      asm volatile("s_waitcnt vmcnt(2)" ::: "memory");     // tile t complete
    } else {
      asm volatile("s_waitcnt vmcnt(0)" ::: "memory");
    }
    const char* Kc = (const char*)&Kl[cur][0];
    const char* Vc = (const char*)&Vl[cur][0];

    // ---- QK^T: s[m][n], lane holds q=(lhi*4+r | m*16), key=l15*4+n ----
    f32x4 s[2][4] = {};
    __builtin_amdgcn_s_setprio(1);
    #pragma unroll
    for (int n = 0; n < 4; ++n) {
      const int key = l15*4 + n;
      bf16x8 kb0 = *(const bf16x8*)(Kc + key*128 + (((lhi    ) ^ (l15>>1))*16));
      bf16x8 kb1 = *(const bf16x8*)(Kc + key*128 + (((4 + lhi) ^ (l15>>1))*16));
      #pragma unroll
      for (int m = 0; m < 2; ++m) {
        s[m][n] = __builtin_amdgcn_mfma_f32_16x16x32_bf16(aq[m][0], kb0, s[m][n], 0, 0, 0);
        s[m][n] = __builtin_amdgcn_mfma_f32_16x16x32_bf16(aq[m][1], kb1, s[m][n], 0, 0, 0);
      }
    }
    __builtin_amdgcn_s_setprio(0);

    // ---- row max over 64 keys (in-lane over n, then 16-lane butterfly) ----
    float tm[2][4];
    #pragma unroll
    for (int m = 0; m < 2; ++m)
      #pragma unroll
      for (int r = 0; r < 4; ++r)
        tm[m][r] = fmaxf(fmaxf(s[m][0][r], s[m][1][r]), fmaxf(s[m][2][r], s[m][3][r]));
    #pragma unroll
    for (int off = 1; off < 16; off <<= 1)
      #pragma unroll
      for (int m = 0; m < 2; ++m)
        #pragma unroll
        for (int r = 0; r < 4; ++r)
          tm[m][r] = fmaxf(tm[m][r], __shfl_xor(tm[m][r], off, 64));

    // ---- online softmax update ----
    float corr[2][4];
    #pragma unroll
    for (int m = 0; m < 2; ++m)
      #pragma unroll
      for (int r = 0; r < 4; ++r) {
        float mnew = fmaxf(mrun[m][r], tm[m][r]);
        corr[m][r] = __expf((mrun[m][r] - mnew) * 0.125f);
        mrun[m][r] = mnew;
        lrun[m][r] *= corr[m][r];
      }
    #pragma unroll
    for (int m = 0; m < 2; ++m)
      #pragma unroll
      for (int n = 0; n < 4; ++n)
        #pragma unroll
        for (int r = 0; r < 4; ++r)
          oacc[m][n][r] *= corr[m][r];

    // ---- P = exp((s-m)/8): packed b64 row-writes into swizzled P tile ----
    #pragma unroll
    for (int m = 0; m < 2; ++m)
      #pragma unroll
      for (int r = 0; r < 4; ++r) {
        bf16x4 pk;
        #pragma unroll
        for (int n = 0; n < 4; ++n) {
          float pv = __expf((s[m][n][r] - mrun[m][r]) * 0.125f);
          lrun[m][r] += pv;
          pk[n] = (__bf16)pv;
        }
        const int row = m*16 + lhi*4 + r;
        *(bf16x4*)((char*)&Pl[w][0] + row*128 + ((l15*8) ^ ((row&7)<<4))) = pk;
      }

    // ---- P A-frags (wave-private; in-wave lgkm ordering) ----
    bf16x8 ap0[2], ap1[2];
    #pragma unroll
    for (int m = 0; m < 2; ++m) {
      const int prow = m*16 + l15;
      const char* pb = (const char*)&Pl[w][0] + prow*128;
      ap0[m] = *(const bf16x8*)(pb + ((      lhi*16) ^ ((prow&7)<<4)));
      ap1[m] = *(const bf16x8*)(pb + ((64 + lhi*16) ^ ((prow&7)<<4)));
    }

    // ---- PV ----
    __builtin_amdgcn_s_setprio(1);
    #pragma unroll
    for (int n = 0; n < 4; ++n) {
      const int d = n*16 + l15;
      bf16x8 vb0 = *(const bf16x8*)(Vc + d*128 + (((lhi    ) ^ (l15&7))*16));
      bf16x8 vb1 = *(const bf16x8*)(Vc + d*128 + (((4 + lhi) ^ (l15&7))*16));
      #pragma unroll
      for (int m = 0; m < 2; ++m) {
        oacc[m][n] = __builtin_amdgcn_mfma_f32_16x16x32_bf16(ap0[m], vb0, oacc[m][n], 0, 0, 0);
        oacc[m][n] = __builtin_amdgcn_mfma_f32_16x16x32_bf16(ap1[m], vb1, oacc[m][n], 0, 0, 0);
      }
    }
    __builtin_amdgcn_s_setprio(0);
    __builtin_amdgcn_s_barrier();   // all waves done reading bufs before next overwrite
  }

  // ---- final row sums + write ----
  #pragma unroll
  for (int off = 1; off < 16; off <<= 1)
    #pragma unroll
    for (int m = 0; m < 2; ++m)
      #pragma unroll
      for (int r = 0; r < 4; ++r)
        lrun[m][r] += __shfl_xor(lrun[m][r], off, 64);
  float rinv[2][4];
  #pragma unroll
  for (int m = 0; m < 2; ++m)
    #pragma unroll
    for (int r = 0; r < 4; ++r) rinv[m][r] = __builtin_amdgcn_rcpf(lrun[m][r]);
  #pragma unroll
  for (int m = 0; m < 2; ++m)
    #pragma unroll
    for (int n = 0; n < 4; ++n)
      #pragma unroll
      for (int r = 0; r < 4; ++r) {
        size_t row = (size_t)b*SEQ + qt*256 + w*32 + m*16 + lhi*4 + r;
        O[row * D_MODEL + h*HEAD_DIM + n*16 + l15] = (__bf16)(oacc[m][n][r] * rinv[m][r]);
      }
}

extern "C" void kernel_launch(void* const* d_in, const int* in_sizes, int n_in,
                              void* d_out, int out_size, void* d_ws, size_t ws_size,
                              hipStream_t stream) {
  const float* x  = (const float*)d_in[0];
  const float* Wq = (const float*)d_in[1];
  const float* Wk = (const float*)d_in[2];
  const float* Wv = (const float*)d_in[3];
  const float* Wo = (const float*)d_in[4];
  float* out = (float*)d_out;

  char* ws = (char*)d_ws;
  size_t off = 0;
  auto alloc = [&](size_t bytes) -> void* {
    void* p = ws + off;
    off += (bytes + 255) & ~(size_t)255;
    return p;
  };
  __bf16* xb    = (__bf16*)alloc((size_t)ROWS * D_MODEL * 2);   // x bf16; reused as attn out
  __bf16* QKVb  = (__bf16*)alloc((size_t)ROWS * QKV_LD * 2);
  __bf16* WqkvT = (__bf16*)alloc((size_t)QKV_LD * D_MODEL * 2);
  __bf16* WoT   = (__bf16*)alloc((size_t)D_MODEL * D_MODEL * 2);
  __bf16* Vtb   = (__bf16*)alloc((size_t)BATCH * 64 * VT_LD * 2);

  k_f32_to_bf16<<<ROWS*D_MODEL/2048, 256, 0, stream>>>(x, xb, ROWS*D_MODEL);
  k_transpose_f32_bf16<<<dim3(D_MODEL/32, D_MODEL/32), 256, 0, stream>>>(Wq, WqkvT, D_MODEL, D_MODEL);
  k_transpose_f32_bf16<<<dim3(HEAD_DIM/32, D_MODEL/32), 256, 0, stream>>>(Wk, WqkvT + (size_t)1024*D_MODEL, D_MODEL, HEAD_DIM);
  k_transpose_f32_bf16<<<dim3(HEAD_DIM/32, D_MODEL/32), 256, 0, stream>>>(Wv, WqkvT + (size_t)1088*D_MODEL, D_MODEL, HEAD_DIM);
  k_transpose_f32_bf16<<<dim3(D_MODEL/32, D_MODEL/32), 256, 0, stream>>>(Wo, WoT, D_MODEL, D_MODEL);

  k_gemm<__bf16><<<dim3(ROWS/128, QKV_LD/128), 256, 0, stream>>>(xb, WqkvT, QKVb, ROWS, QKV_LD, D_MODEL);
  k_vt_split<<<dim3(SEQ/64, BATCH), 256, 0, stream>>>(QKVb, Vtb);
  k_attn<<<dim3(SEQ/256, N_HEADS, BATCH), 512, 0, stream>>>(QKVb, Vtb, xb);
  k_gemm<float><<<dim3(ROWS/128, D_MODEL/128), 256, 0, stream>>>(xb, WoT, out, ROWS, D_MODEL, D_MODEL);
}

// Round 7
// 263.811 us; speedup vs baseline: 2.4512x; 1.2256x over previous
//
#include <hip/hip_runtime.h>
#include <hip/hip_bf16.h>

typedef __bf16  bf16x8  __attribute__((ext_vector_type(8)));
typedef __bf16  bf16x4  __attribute__((ext_vector_type(4)));
typedef float   f32x4   __attribute__((ext_vector_type(4)));
typedef unsigned short ushort8 __attribute__((ext_vector_type(8)));

#define D_MODEL 1024
#define HEAD_DIM 64
#define N_HEADS 16
#define BATCH 4
#define SEQ 2048
#define ROWS (BATCH*SEQ)   // 8192
#define QKV_LD 1152        // 1024 (Q) + 64 (K) + 64 (V)
#define VT_LD 2080         // padded: 4160 B rows, breaks 4KB channel aliasing

#define AS1 __attribute__((address_space(1)))
#define AS3 __attribute__((address_space(3)))

// ---------------- fp32 -> bf16 convert (vectorized) ----------------
__global__ __launch_bounds__(256) void k_f32_to_bf16(const float* __restrict__ in,
                                                     __bf16* __restrict__ out, int n) {
  int i = (blockIdx.x * 256 + threadIdx.x) * 8;
  if (i >= n) return;
  float4 a = *(const float4*)(in + i);
  float4 b = *(const float4*)(in + i + 4);
  __bf16 r[8] __attribute__((aligned(16))) =
      {(__bf16)a.x,(__bf16)a.y,(__bf16)a.z,(__bf16)a.w,
       (__bf16)b.x,(__bf16)b.y,(__bf16)b.z,(__bf16)b.w};
  *(ushort8*)(out + i) = *(const ushort8*)r;
}

// ---------------- transpose + convert: in fp32 [R][C] -> out bf16 [C][R'] ----------------
__global__ __launch_bounds__(256) void k_transpose_f32_bf16(const float* __restrict__ in,
                                                            __bf16* __restrict__ out,
                                                            int R, int C) {
  __shared__ float t[32][33];
  int tx = threadIdx.x & 31, ty = threadIdx.x >> 5;   // 32x8
  int r0 = blockIdx.y * 32, c0 = blockIdx.x * 32;
  #pragma unroll
  for (int i = 0; i < 4; ++i)
    t[ty + i*8][tx] = in[(size_t)(r0 + ty + i*8) * C + c0 + tx];
  __syncthreads();
  #pragma unroll
  for (int i = 0; i < 4; ++i)
    out[(size_t)(c0 + ty + i*8) * R + r0 + tx] = (__bf16)t[tx][ty + i*8];
}

// ---------------- bf16 MFMA GEMM: C[M][N] = A[M][K] * Bt[N][K]^T ----------------
template<typename OUT_T>
__global__ __launch_bounds__(256) void k_gemm(const __bf16* __restrict__ A,
                                              const __bf16* __restrict__ Bt,
                                              OUT_T* __restrict__ C,
                                              int M, int N, int K) {
  __shared__ __bf16 As[128*32] __attribute__((aligned(16)));
  __shared__ __bf16 Bs[128*32] __attribute__((aligned(16)));
  const int tid  = threadIdx.x;
  const int lane = tid & 63, wave = tid >> 6;
  const int wm = wave >> 1, wn = wave & 1;
  const int l15 = lane & 15, lhi = lane >> 4;
  const int arow0 = blockIdx.x * 128;
  const int brow0 = blockIdx.y * 128;
  f32x4 acc[4][4] = {};
  const int srow = lane >> 2;        // 0..15
  const int scol = (lane & 3) * 8;   // 0,8,16,24

  for (int kt = 0; kt < K; kt += 32) {
    __syncthreads();
    #pragma unroll
    for (int i = 0; i < 2; ++i) {
      int chunk = i*4 + wave;
      int r = chunk*16 + srow;
      __builtin_amdgcn_global_load_lds(
          (const AS1 unsigned int*)(A  + (size_t)(arow0 + r)*K + kt + scol),
          (AS3 unsigned int*)(As + chunk*512), 16, 0, 0);
      __builtin_amdgcn_global_load_lds(
          (const AS1 unsigned int*)(Bt + (size_t)(brow0 + r)*K + kt + scol),
          (AS3 unsigned int*)(Bs + chunk*512), 16, 0, 0);
    }
    __syncthreads();
    bf16x8 af[4], bfr[4];
    #pragma unroll
    for (int m = 0; m < 4; ++m)
      af[m] = *(const bf16x8*)(As + (wm*64 + m*16 + l15)*32 + lhi*8);
    #pragma unroll
    for (int n = 0; n < 4; ++n)
      bfr[n] = *(const bf16x8*)(Bs + (wn*64 + n*16 + l15)*32 + lhi*8);
    #pragma unroll
    for (int m = 0; m < 4; ++m)
      #pragma unroll
      for (int n = 0; n < 4; ++n)
        acc[m][n] = __builtin_amdgcn_mfma_f32_16x16x32_bf16(af[m], bfr[n], acc[m][n], 0, 0, 0);
  }
  #pragma unroll
  for (int m = 0; m < 4; ++m)
    #pragma unroll
    for (int n = 0; n < 4; ++n) {
      int row = arow0 + wm*64 + m*16 + lhi*4;
      int col = brow0 + wn*64 + n*16 + l15;
      #pragma unroll
      for (int r = 0; r < 4; ++r)
        C[(size_t)(row + r) * N + col] = (OUT_T)acc[m][n][r];
    }
}

// ---------------- split V cols of QKV -> Vt (transposed V, padded stride) ----------------
__global__ __launch_bounds__(256) void k_vt_split(const __bf16* __restrict__ QKV,
                                                  __bf16* __restrict__ Vt) {
  __shared__ __bf16 t[64][72] __attribute__((aligned(16)));
  int st = blockIdx.x, b = blockIdx.y;
  int tid = threadIdx.x;
  int rr = tid >> 3, cc = (tid & 7) * 8;
  #pragma unroll
  for (int i = 0; i < 2; ++i) {
    int s = rr + i*32;
    *(ushort8*)&t[s][cc] =
      *(const ushort8*)(QKV + (size_t)(b*SEQ + st*64 + s) * QKV_LD + 1088 + cc);
  }
  __syncthreads();
  #pragma unroll
  for (int i = 0; i < 2; ++i) {
    int d = rr + i*32;
    __bf16 tmp[8] __attribute__((aligned(16)));
    #pragma unroll
    for (int j = 0; j < 8; ++j) tmp[j] = t[cc + j][d];
    *(ushort8*)(Vt + (size_t)(b*64 + d) * VT_LD + st*64 + cc) = *(const ushort8*)tmp;
  }
}

// ---------------- flash attention (MQA), swapped-QK softmax ----------------
// grid: (SEQ/256, N_HEADS, BATCH), 512 thr. Wave w owns q-rows [w*32, w*32+32).
// QK computed as mfma(K,Q): s[m][n] holds q = m*16+l15, key = n*16+lhi*4+r.
// Row state lives in 4 lanes (same l15, lhi=0..3) -> 2-step xor-16/32 reduce.
// K_lds[key][dim] & V_lds[d][key] XOR-swz blocks by (row&7); P[q][key] XOR-swz by (q&7).
__global__ __launch_bounds__(512, 4) void k_attn(const __bf16* __restrict__ QKV, // [8192][1152]
                                                 const __bf16* __restrict__ Vt,  // [B][64][VT_LD]
                                                 __bf16* __restrict__ O) {       // [8192][1024]
  __shared__ __bf16 Kl[2][64*64];   // 8KB per buf, linear dest for global_load_lds
  __shared__ __bf16 Vl[2][64*64];
  __shared__ __bf16 Pl[8][32*64];   // per-wave P tile (32 q-rows x 64 keys)
  const int qt = blockIdx.x, h = blockIdx.y, b = blockIdx.z;
  const int tid = threadIdx.x, lane = tid & 63, w = tid >> 6;
  const int l15 = lane & 15, lhi = lane >> 4;
  const int l7 = l15 & 7;

  // staging: wave w covers rows w*8..w*8+7 of the 64-row tile, 8 lanes/row.
  // Both K and V store physical block = logical ^ (row&7); row&7 == srow here.
  const int srow = lane >> 3;              // 0..7
  const int j8   = lane & 7;               // physical 16B block this lane writes
  const int row_t = w*8 + srow;            // tile row (key for K, d for V)
  const int jsrc = j8 ^ srow;              // inverse-swizzled source block
  const __bf16* Kg = QKV + (size_t)b*SEQ*QKV_LD + 1024;
  const __bf16* Vg = Vt  + (size_t)b*64*VT_LD;

  auto stage = [&](int t, int buf) {
    __builtin_amdgcn_global_load_lds(
        (const AS1 unsigned int*)(Kg + (size_t)(t*64 + row_t)*QKV_LD + jsrc*8),
        (AS3 unsigned int*)(&Kl[buf][0] + w*512), 16, 0, 0);
    __builtin_amdgcn_global_load_lds(
        (const AS1 unsigned int*)(Vg + (size_t)row_t*VT_LD + t*64 + jsrc*8),
        (AS3 unsigned int*)(&Vl[buf][0] + w*512), 16, 0, 0);
  };

  stage(0, 0);

  // Q fragments (2 m-tiles x 2 dim-halves); MFMA B-operand (col=q=l15, k=dim lhi*8+j)
  bf16x8 aq[2][2];
  {
    const __bf16* qp = QKV + (size_t)(b*SEQ + qt*256 + w*32 + l15)*QKV_LD + h*HEAD_DIM;
    aq[0][0] = *(const bf16x8*)(qp +               lhi*8);
    aq[0][1] = *(const bf16x8*)(qp +          32 + lhi*8);
    aq[1][0] = *(const bf16x8*)(qp + 16*QKV_LD +      lhi*8);
    aq[1][1] = *(const bf16x8*)(qp + 16*QKV_LD + 32 + lhi*8);
  }

  f32x4 oacc[2][4] = {};
  float mrun[2] = {-__builtin_inff(), -__builtin_inff()};
  float lrun[2] = {0.f, 0.f};

  asm volatile("s_waitcnt vmcnt(0)" ::: "memory");
  __builtin_amdgcn_s_barrier();

  for (int t = 0; t < SEQ/64; ++t) {
    const int cur = t & 1;
    if (t < SEQ/64 - 1) {
      stage(t+1, cur^1);                                   // prefetch stays in flight
      asm volatile("s_waitcnt vmcnt(2)" ::: "memory");     // tile t complete
    } else {
      asm volatile("s_waitcnt vmcnt(0)" ::: "memory");
    }
    const char* Kc = (const char*)&Kl[cur][0];
    const char* Vc = (const char*)&Vl[cur][0];

    // ---- QK^T (swapped): s[m][n] = K(n-block) x Q(m-tile); lane: q=l15, keys lhi*4+r ----
    f32x4 s[2][4] = {};
    __builtin_amdgcn_s_setprio(1);
    #pragma unroll
    for (int n = 0; n < 4; ++n) {
      const int key = n*16 + l15;
      bf16x8 kb0 = *(const bf16x8*)(Kc + key*128 + (((    lhi) ^ l7)*16));
      bf16x8 kb1 = *(const bf16x8*)(Kc + key*128 + (((4 + lhi) ^ l7)*16));
      #pragma unroll
      for (int m = 0; m < 2; ++m) {
        s[m][n] = __builtin_amdgcn_mfma_f32_16x16x32_bf16(kb0, aq[m][0], s[m][n], 0, 0, 0);
        s[m][n] = __builtin_amdgcn_mfma_f32_16x16x32_bf16(kb1, aq[m][1], s[m][n], 0, 0, 0);
      }
    }
    __builtin_amdgcn_s_setprio(0);

    // ---- row max: in-lane over this lane's 16 keys, then xor-16/32 across the 4
    //      sibling lanes holding the same q-row (CORRECTNESS FIX vs prev round) ----
    float tm[2];
    #pragma unroll
    for (int m = 0; m < 2; ++m) {
      float a0 = fmaxf(fmaxf(s[m][0][0], s[m][0][1]), fmaxf(s[m][0][2], s[m][0][3]));
      float a1 = fmaxf(fmaxf(s[m][1][0], s[m][1][1]), fmaxf(s[m][1][2], s[m][1][3]));
      float a2 = fmaxf(fmaxf(s[m][2][0], s[m][2][1]), fmaxf(s[m][2][2], s[m][2][3]));
      float a3 = fmaxf(fmaxf(s[m][3][0], s[m][3][1]), fmaxf(s[m][3][2], s[m][3][3]));
      tm[m] = fmaxf(fmaxf(a0, a1), fmaxf(a2, a3));
      tm[m] = fmaxf(tm[m], __shfl_xor(tm[m], 16, 64));
      tm[m] = fmaxf(tm[m], __shfl_xor(tm[m], 32, 64));
    }

    // ---- defer-max (T13): rescale only when max grows past THR=64 (pre-scale) ----
    int nogrow = (tm[0] <= mrun[0] + 64.f) && (tm[1] <= mrun[1] + 64.f);
    if (!__all(nogrow)) {
      float corr[2];
      #pragma unroll
      for (int m = 0; m < 2; ++m) {
        float mnew = fmaxf(mrun[m], tm[m]);
        corr[m] = __expf((mrun[m] - mnew) * 0.125f);
        mrun[m] = mnew;
        lrun[m] *= corr[m];
      }
      #pragma unroll
      for (int m = 0; m < 2; ++m) {
        float cb[4];
        #pragma unroll
        for (int r = 0; r < 4; ++r) cb[r] = __shfl(corr[m], lhi*4 + r, 64);
        #pragma unroll
        for (int n = 0; n < 4; ++n)
          #pragma unroll
          for (int r = 0; r < 4; ++r)
            oacc[m][n][r] *= cb[r];
      }
    }

    // ---- P = exp((s-m)/8), pack 4 keys -> one b64 store into swizzled P tile ----
    #pragma unroll
    for (int m = 0; m < 2; ++m) {
      const int prow = m*16 + l15;
      #pragma unroll
      for (int n = 0; n < 4; ++n) {
        bf16x4 pk;
        #pragma unroll
        for (int r = 0; r < 4; ++r) {
          float pv = __expf((s[m][n][r] - mrun[m]) * 0.125f);
          lrun[m] += pv;
          pk[r] = (__bf16)pv;
        }
        const int blk = (n*2 + (lhi>>1)) ^ l7;   // 16B block, XOR by q&7
        *(bf16x4*)((char*)&Pl[w][0] + prow*128 + blk*16 + (lhi&1)*8) = pk;
      }
    }

    // ---- P A-frags (wave-private; in-wave lgkm ordering) ----
    bf16x8 ap0[2], ap1[2];
    #pragma unroll
    for (int m = 0; m < 2; ++m) {
      const char* pb = (const char*)&Pl[w][0] + (m*16 + l15)*128;
      ap0[m] = *(const bf16x8*)(pb + (((    lhi) ^ l7)*16));
      ap1[m] = *(const bf16x8*)(pb + (((4 + lhi) ^ l7)*16));
    }

    // ---- PV ----
    __builtin_amdgcn_s_setprio(1);
    #pragma unroll
    for (int n = 0; n < 4; ++n) {
      const int d = n*16 + l15;
      bf16x8 vb0 = *(const bf16x8*)(Vc + d*128 + (((    lhi) ^ l7)*16));
      bf16x8 vb1 = *(const bf16x8*)(Vc + d*128 + (((4 + lhi) ^ l7)*16));
      #pragma unroll
      for (int m = 0; m < 2; ++m) {
        oacc[m][n] = __builtin_amdgcn_mfma_f32_16x16x32_bf16(ap0[m], vb0, oacc[m][n], 0, 0, 0);
        oacc[m][n] = __builtin_amdgcn_mfma_f32_16x16x32_bf16(ap1[m], vb1, oacc[m][n], 0, 0, 0);
      }
    }
    __builtin_amdgcn_s_setprio(0);
    __builtin_amdgcn_s_barrier();   // all waves done reading bufs before next overwrite
  }

  // ---- reduce l across the 4 sibling lanes, broadcast to oacc rows, write ----
  #pragma unroll
  for (int m = 0; m < 2; ++m) {
    lrun[m] += __shfl_xor(lrun[m], 16, 64);
    lrun[m] += __shfl_xor(lrun[m], 32, 64);
  }
  float rinv[2][4];
  #pragma unroll
  for (int m = 0; m < 2; ++m)
    #pragma unroll
    for (int r = 0; r < 4; ++r)
      rinv[m][r] = __builtin_amdgcn_rcpf(__shfl(lrun[m], lhi*4 + r, 64));
  #pragma unroll
  for (int m = 0; m < 2; ++m)
    #pragma unroll
    for (int n = 0; n < 4; ++n)
      #pragma unroll
      for (int r = 0; r < 4; ++r) {
        size_t row = (size_t)b*SEQ + qt*256 + w*32 + m*16 + lhi*4 + r;
        O[row * D_MODEL + h*HEAD_DIM + n*16 + l15] = (__bf16)(oacc[m][n][r] * rinv[m][r]);
      }
}

extern "C" void kernel_launch(void* const* d_in, const int* in_sizes, int n_in,
                              void* d_out, int out_size, void* d_ws, size_t ws_size,
                              hipStream_t stream) {
  const float* x  = (const float*)d_in[0];
  const float* Wq = (const float*)d_in[1];
  const float* Wk = (const float*)d_in[2];
  const float* Wv = (const float*)d_in[3];
  const float* Wo = (const float*)d_in[4];
  float* out = (float*)d_out;

  char* ws = (char*)d_ws;
  size_t off = 0;
  auto alloc = [&](size_t bytes) -> void* {
    void* p = ws + off;
    off += (bytes + 255) & ~(size_t)255;
    return p;
  };
  __bf16* xb    = (__bf16*)alloc((size_t)ROWS * D_MODEL * 2);   // x bf16; reused as attn out
  __bf16* QKVb  = (__bf16*)alloc((size_t)ROWS * QKV_LD * 2);
  __bf16* WqkvT = (__bf16*)alloc((size_t)QKV_LD * D_MODEL * 2);
  __bf16* WoT   = (__bf16*)alloc((size_t)D_MODEL * D_MODEL * 2);
  __bf16* Vtb   = (__bf16*)alloc((size_t)BATCH * 64 * VT_LD * 2);

  k_f32_to_bf16<<<ROWS*D_MODEL/2048, 256, 0, stream>>>(x, xb, ROWS*D_MODEL);
  k_transpose_f32_bf16<<<dim3(D_MODEL/32, D_MODEL/32), 256, 0, stream>>>(Wq, WqkvT, D_MODEL, D_MODEL);
  k_transpose_f32_bf16<<<dim3(HEAD_DIM/32, D_MODEL/32), 256, 0, stream>>>(Wk, WqkvT + (size_t)1024*D_MODEL, D_MODEL, HEAD_DIM);
  k_transpose_f32_bf16<<<dim3(HEAD_DIM/32, D_MODEL/32), 256, 0, stream>>>(Wv, WqkvT + (size_t)1088*D_MODEL, D_MODEL, HEAD_DIM);
  k_transpose_f32_bf16<<<dim3(D_MODEL/32, D_MODEL/32), 256, 0, stream>>>(Wo, WoT, D_MODEL, D_MODEL);

  k_gemm<__bf16><<<dim3(ROWS/128, QKV_LD/128), 256, 0, stream>>>(xb, WqkvT, QKVb, ROWS, QKV_LD, D_MODEL);
  k_vt_split<<<dim3(SEQ/64, BATCH), 256, 0, stream>>>(QKVb, Vtb);
  k_attn<<<dim3(SEQ/256, N_HEADS, BATCH), 512, 0, stream>>>(QKVb, Vtb, xb);
  k_gemm<float><<<dim3(ROWS/128, D_MODEL/128), 256, 0, stream>>>(xb, WoT, out, ROWS, D_MODEL, D_MODEL);
}

// Round 9
// 244.535 us; speedup vs baseline: 2.6444x; 1.0788x over previous
//
#include <hip/hip_runtime.h>
#include <hip/hip_bf16.h>

typedef __bf16  bf16x8  __attribute__((ext_vector_type(8)));
typedef __bf16  bf16x4  __attribute__((ext_vector_type(4)));
typedef float   f32x4   __attribute__((ext_vector_type(4)));
typedef unsigned short ushort8 __attribute__((ext_vector_type(8)));

#define D_MODEL 1024
#define HEAD_DIM 64
#define N_HEADS 16
#define BATCH 4
#define SEQ 2048
#define ROWS (BATCH*SEQ)   // 8192
#define QKV_LD 1152        // 1024 (Q) + 64 (K) + 64 (V)
#define VT_LD 2080         // padded: 4160 B rows, breaks 4KB channel aliasing

#define AS1 __attribute__((address_space(1)))
#define AS3 __attribute__((address_space(3)))

// raw v_exp_f32: D = 2^S0 (exp2-domain softmax; scale folded into Wq)
static __device__ inline float exp2_fast(float x) {
  float r; asm("v_exp_f32 %0, %1" : "=v"(r) : "v"(x)); return r;
}

// ---------------- fp32 -> bf16 convert (vectorized) ----------------
__global__ __launch_bounds__(256) void k_f32_to_bf16(const float* __restrict__ in,
                                                     __bf16* __restrict__ out, int n) {
  int i = (blockIdx.x * 256 + threadIdx.x) * 8;
  if (i >= n) return;
  float4 a = *(const float4*)(in + i);
  float4 b = *(const float4*)(in + i + 4);
  __bf16 r[8] __attribute__((aligned(16))) =
      {(__bf16)a.x,(__bf16)a.y,(__bf16)a.z,(__bf16)a.w,
       (__bf16)b.x,(__bf16)b.y,(__bf16)b.z,(__bf16)b.w};
  *(ushort8*)(out + i) = *(const ushort8*)r;
}

// ---------------- transpose + convert + scale: fp32 [R][C] -> bf16 [C][R] ----------------
__global__ __launch_bounds__(256) void k_transpose_f32_bf16(const float* __restrict__ in,
                                                            __bf16* __restrict__ out,
                                                            int R, int C, float scale) {
  __shared__ float t[32][33];
  int tx = threadIdx.x & 31, ty = threadIdx.x >> 5;   // 32x8
  int r0 = blockIdx.y * 32, c0 = blockIdx.x * 32;
  #pragma unroll
  for (int i = 0; i < 4; ++i)
    t[ty + i*8][tx] = in[(size_t)(r0 + ty + i*8) * C + c0 + tx];
  __syncthreads();
  #pragma unroll
  for (int i = 0; i < 4; ++i)
    out[(size_t)(c0 + ty + i*8) * R + r0 + tx] = (__bf16)(t[tx][ty + i*8] * scale);
}

// ---------------- bf16 MFMA GEMM: C[M][N] = A[M][K] * Bt[N][K]^T ----------------
// 128x128 tile, BK=32, 2-phase double-buffered global_load_lds (T3-minimum recipe):
// stage(t+1) issued BEFORE compute of t; one vmcnt(0)+barrier per tile.
template<typename OUT_T>
__global__ __launch_bounds__(256) void k_gemm(const __bf16* __restrict__ A,
                                              const __bf16* __restrict__ Bt,
                                              OUT_T* __restrict__ C,
                                              int M, int N, int K) {
  __shared__ __bf16 As[2][128*32] __attribute__((aligned(16)));
  __shared__ __bf16 Bs[2][128*32] __attribute__((aligned(16)));
  const int tid  = threadIdx.x;
  const int lane = tid & 63, wave = tid >> 6;
  const int wm = wave >> 1, wn = wave & 1;
  const int l15 = lane & 15, lhi = lane >> 4;
  const int arow0 = blockIdx.x * 128;
  const int brow0 = blockIdx.y * 128;
  f32x4 acc[4][4] = {};
  const int srow = lane >> 2;        // 0..15
  const int scol = (lane & 3) * 8;   // 0,8,16,24
  const int nt = K >> 5;

  auto stage = [&](int t, int buf) {
    #pragma unroll
    for (int i = 0; i < 2; ++i) {
      int chunk = i*4 + wave;              // 0..7, 16 rows each
      int r = chunk*16 + srow;
      __builtin_amdgcn_global_load_lds(
          (const AS1 unsigned int*)(A  + (size_t)(arow0 + r)*K + t*32 + scol),
          (AS3 unsigned int*)(&As[buf][0] + chunk*512), 16, 0, 0);
      __builtin_amdgcn_global_load_lds(
          (const AS1 unsigned int*)(Bt + (size_t)(brow0 + r)*K + t*32 + scol),
          (AS3 unsigned int*)(&Bs[buf][0] + chunk*512), 16, 0, 0);
    }
  };

  stage(0, 0);
  asm volatile("s_waitcnt vmcnt(0)" ::: "memory");
  __builtin_amdgcn_s_barrier();

  for (int t = 0; t < nt; ++t) {
    const int cur = t & 1;
    if (t + 1 < nt) stage(t + 1, cur ^ 1);   // prefetch overlaps this tile's compute
    bf16x8 af[4], bfr[4];
    #pragma unroll
    for (int m = 0; m < 4; ++m)
      af[m] = *(const bf16x8*)(&As[cur][0] + (wm*64 + m*16 + l15)*32 + lhi*8);
    #pragma unroll
    for (int n = 0; n < 4; ++n)
      bfr[n] = *(const bf16x8*)(&Bs[cur][0] + (wn*64 + n*16 + l15)*32 + lhi*8);
    #pragma unroll
    for (int m = 0; m < 4; ++m)
      #pragma unroll
      for (int n = 0; n < 4; ++n)
        acc[m][n] = __builtin_amdgcn_mfma_f32_16x16x32_bf16(af[m], bfr[n], acc[m][n], 0, 0, 0);
    asm volatile("s_waitcnt vmcnt(0)" ::: "memory");   // next tile landed (had MFMA phase to do so)
    __builtin_amdgcn_s_barrier();
  }
  // epilogue: D layout col=lane&15, row=(lane>>4)*4+reg  [HW-verified]
  #pragma unroll
  for (int m = 0; m < 4; ++m)
    #pragma unroll
    for (int n = 0; n < 4; ++n) {
      int row = arow0 + wm*64 + m*16 + lhi*4;
      int col = brow0 + wn*64 + n*16 + l15;
      #pragma unroll
      for (int r = 0; r < 4; ++r)
        C[(size_t)(row + r) * N + col] = (OUT_T)acc[m][n][r];
    }
}

// ---------------- split V cols of QKV -> Vt (transposed V, padded stride) ----------------
__global__ __launch_bounds__(256) void k_vt_split(const __bf16* __restrict__ QKV,
                                                  __bf16* __restrict__ Vt) {
  __shared__ __bf16 t[64][72] __attribute__((aligned(16)));
  int st = blockIdx.x, b = blockIdx.y;
  int tid = threadIdx.x;
  int rr = tid >> 3, cc = (tid & 7) * 8;
  #pragma unroll
  for (int i = 0; i < 2; ++i) {
    int s = rr + i*32;
    *(ushort8*)&t[s][cc] =
      *(const ushort8*)(QKV + (size_t)(b*SEQ + st*64 + s) * QKV_LD + 1088 + cc);
  }
  __syncthreads();
  #pragma unroll
  for (int i = 0; i < 2; ++i) {
    int d = rr + i*32;
    __bf16 tmp[8] __attribute__((aligned(16)));
    #pragma unroll
    for (int j = 0; j < 8; ++j) tmp[j] = t[cc + j][d];
    *(ushort8*)(Vt + (size_t)(b*64 + d) * VT_LD + st*64 + cc) = *(const ushort8*)tmp;
  }
}

// ---------------- flash attention (MQA), swapped-QK softmax, exp2 domain ----------------
// grid: (SEQ/256, N_HEADS, BATCH), 512 thr. Wave w owns q-rows [w*32, w*32+32).
// Q pre-scaled by 0.125*log2(e) in the Wq transpose -> P = 2^(s - m), no muls in exp chain.
// QK computed as mfma(K,Q): s[m][n] holds q = m*16+l15, key = n*16+lhi*4+r.
// Row state lives in 4 lanes (same l15, lhi=0..3) -> 2-step xor-16/32 reduce.
__global__ __launch_bounds__(512, 4) void k_attn(const __bf16* __restrict__ QKV, // [8192][1152]
                                                 const __bf16* __restrict__ Vt,  // [B][64][VT_LD]
                                                 __bf16* __restrict__ O) {       // [8192][1024]
  __shared__ __bf16 Kl[2][64*64];   // 8KB per buf, linear dest for global_load_lds
  __shared__ __bf16 Vl[2][64*64];
  __shared__ __bf16 Pl[8][32*64];   // per-wave P tile (32 q-rows x 64 keys)
  const int qt = blockIdx.x, h = blockIdx.y, b = blockIdx.z;
  const int tid = threadIdx.x, lane = tid & 63, w = tid >> 6;
  const int l15 = lane & 15, lhi = lane >> 4;
  const int l7 = l15 & 7;

  const int srow = lane >> 3;              // 0..7
  const int j8   = lane & 7;               // physical 16B block this lane writes
  const int row_t = w*8 + srow;            // tile row (key for K, d for V)
  const int jsrc = j8 ^ srow;              // inverse-swizzled source block
  const __bf16* Kg = QKV + (size_t)b*SEQ*QKV_LD + 1024;
  const __bf16* Vg = Vt  + (size_t)b*64*VT_LD;

  auto stage = [&](int t, int buf) {
    __builtin_amdgcn_global_load_lds(
        (const AS1 unsigned int*)(Kg + (size_t)(t*64 + row_t)*QKV_LD + jsrc*8),
        (AS3 unsigned int*)(&Kl[buf][0] + w*512), 16, 0, 0);
    __builtin_amdgcn_global_load_lds(
        (const AS1 unsigned int*)(Vg + (size_t)row_t*VT_LD + t*64 + jsrc*8),
        (AS3 unsigned int*)(&Vl[buf][0] + w*512), 16, 0, 0);
  };

  stage(0, 0);

  // Q fragments (2 m-tiles x 2 dim-halves); MFMA B-operand (col=q=l15, k=dim lhi*8+j)
  bf16x8 aq[2][2];
  {
    const __bf16* qp = QKV + (size_t)(b*SEQ + qt*256 + w*32 + l15)*QKV_LD + h*HEAD_DIM;
    aq[0][0] = *(const bf16x8*)(qp +               lhi*8);
    aq[0][1] = *(const bf16x8*)(qp +          32 + lhi*8);
    aq[1][0] = *(const bf16x8*)(qp + 16*QKV_LD +      lhi*8);
    aq[1][1] = *(const bf16x8*)(qp + 16*QKV_LD + 32 + lhi*8);
  }

  f32x4 oacc[2][4] = {};
  float mrun[2] = {-__builtin_inff(), -__builtin_inff()};
  float lrun[2] = {0.f, 0.f};

  asm volatile("s_waitcnt vmcnt(0)" ::: "memory");
  __builtin_amdgcn_s_barrier();

  for (int t = 0; t < SEQ/64; ++t) {
    const int cur = t & 1;
    if (t < SEQ/64 - 1) {
      stage(t+1, cur^1);                                   // prefetch stays in flight
      asm volatile("s_waitcnt vmcnt(2)" ::: "memory");     // tile t complete
    } else {
      asm volatile("s_waitcnt vmcnt(0)" ::: "memory");
    }
    const char* Kc = (const char*)&Kl[cur][0];
    const char* Vc = (const char*)&Vl[cur][0];

    // ---- QK^T (swapped): s[m][n] = K(n-block) x Q(m-tile); lane: q=l15, keys lhi*4+r ----
    f32x4 s[2][4] = {};
    __builtin_amdgcn_s_setprio(1);
    #pragma unroll
    for (int n = 0; n < 4; ++n) {
      const int key = n*16 + l15;
      bf16x8 kb0 = *(const bf16x8*)(Kc + key*128 + (((    lhi) ^ l7)*16));
      bf16x8 kb1 = *(const bf16x8*)(Kc + key*128 + (((4 + lhi) ^ l7)*16));
      #pragma unroll
      for (int m = 0; m < 2; ++m) {
        s[m][n] = __builtin_amdgcn_mfma_f32_16x16x32_bf16(kb0, aq[m][0], s[m][n], 0, 0, 0);
        s[m][n] = __builtin_amdgcn_mfma_f32_16x16x32_bf16(kb1, aq[m][1], s[m][n], 0, 0, 0);
      }
    }
    __builtin_amdgcn_s_setprio(0);

    // ---- row max: in-lane 16 keys, then xor-16/32 across the 4 sibling lanes ----
    float tm[2];
    #pragma unroll
    for (int m = 0; m < 2; ++m) {
      float a0 = fmaxf(fmaxf(s[m][0][0], s[m][0][1]), fmaxf(s[m][0][2], s[m][0][3]));
      float a1 = fmaxf(fmaxf(s[m][1][0], s[m][1][1]), fmaxf(s[m][1][2], s[m][1][3]));
      float a2 = fmaxf(fmaxf(s[m][2][0], s[m][2][1]), fmaxf(s[m][2][2], s[m][2][3]));
      float a3 = fmaxf(fmaxf(s[m][3][0], s[m][3][1]), fmaxf(s[m][3][2], s[m][3][3]));
      tm[m] = fmaxf(fmaxf(a0, a1), fmaxf(a2, a3));
      tm[m] = fmaxf(tm[m], __shfl_xor(tm[m], 16, 64));
      tm[m] = fmaxf(tm[m], __shfl_xor(tm[m], 32, 64));
    }

    // ---- defer-max (T13): rescale only when max grows past THR=8 (log2 units, P<=256) ----
    int nogrow = (tm[0] <= mrun[0] + 8.f) && (tm[1] <= mrun[1] + 8.f);
    if (!__all(nogrow)) {
      float corr[2];
      #pragma unroll
      for (int m = 0; m < 2; ++m) {
        float mnew = fmaxf(mrun[m], tm[m]);
        corr[m] = exp2_fast(mrun[m] - mnew);
        mrun[m] = mnew;
        lrun[m] *= corr[m];
      }
      #pragma unroll
      for (int m = 0; m < 2; ++m) {
        float cb[4];
        #pragma unroll
        for (int r = 0; r < 4; ++r) cb[r] = __shfl(corr[m], lhi*4 + r, 64);
        #pragma unroll
        for (int n = 0; n < 4; ++n)
          #pragma unroll
          for (int r = 0; r < 4; ++r)
            oacc[m][n][r] *= cb[r];
      }
    }

    // ---- P = 2^(s-m), pack 4 keys -> one b64 store into swizzled P tile ----
    #pragma unroll
    for (int m = 0; m < 2; ++m) {
      const int prow = m*16 + l15;
      #pragma unroll
      for (int n = 0; n < 4; ++n) {
        bf16x4 pk;
        #pragma unroll
        for (int r = 0; r < 4; ++r) {
          float pv = exp2_fast(s[m][n][r] - mrun[m]);
          lrun[m] += pv;
          pk[r] = (__bf16)pv;
        }
        const int blk = (n*2 + (lhi>>1)) ^ l7;   // 16B block, XOR by q&7
        *(bf16x4*)((char*)&Pl[w][0] + prow*128 + blk*16 + (lhi&1)*8) = pk;
      }
    }

    // ---- P A-frags (wave-private; in-wave lgkm ordering) ----
    bf16x8 ap0[2], ap1[2];
    #pragma unroll
    for (int m = 0; m < 2; ++m) {
      const char* pb = (const char*)&Pl[w][0] + (m*16 + l15)*128;
      ap0[m] = *(const bf16x8*)(pb + (((    lhi) ^ l7)*16));
      ap1[m] = *(const bf16x8*)(pb + (((4 + lhi) ^ l7)*16));
    }

    // ---- PV ----
    __builtin_amdgcn_s_setprio(1);
    #pragma unroll
    for (int n = 0; n < 4; ++n) {
      const int d = n*16 + l15;
      bf16x8 vb0 = *(const bf16x8*)(Vc + d*128 + (((    lhi) ^ l7)*16));
      bf16x8 vb1 = *(const bf16x8*)(Vc + d*128 + (((4 + lhi) ^ l7)*16));
      #pragma unroll
      for (int m = 0; m < 2; ++m) {
        oacc[m][n] = __builtin_amdgcn_mfma_f32_16x16x32_bf16(ap0[m], vb0, oacc[m][n], 0, 0, 0);
        oacc[m][n] = __builtin_amdgcn_mfma_f32_16x16x32_bf16(ap1[m], vb1, oacc[m][n], 0, 0, 0);
      }
    }
    __builtin_amdgcn_s_setprio(0);
    __builtin_amdgcn_s_barrier();   // all waves done reading bufs before next overwrite
  }

  // ---- reduce l across the 4 sibling lanes, broadcast to oacc rows, write ----
  #pragma unroll
  for (int m = 0; m < 2; ++m) {
    lrun[m] += __shfl_xor(lrun[m], 16, 64);
    lrun[m] += __shfl_xor(lrun[m], 32, 64);
  }
  float rinv[2][4];
  #pragma unroll
  for (int m = 0; m < 2; ++m)
    #pragma unroll
    for (int r = 0; r < 4; ++r)
      rinv[m][r] = __builtin_amdgcn_rcpf(__shfl(lrun[m], lhi*4 + r, 64));
  #pragma unroll
  for (int m = 0; m < 2; ++m)
    #pragma unroll
    for (int n = 0; n < 4; ++n)
      #pragma unroll
      for (int r = 0; r < 4; ++r) {
        size_t row = (size_t)b*SEQ + qt*256 + w*32 + m*16 + lhi*4 + r;
        O[row * D_MODEL + h*HEAD_DIM + n*16 + l15] = (__bf16)(oacc[m][n][r] * rinv[m][r]);
      }
}

extern "C" void kernel_launch(void* const* d_in, const int* in_sizes, int n_in,
                              void* d_out, int out_size, void* d_ws, size_t ws_size,
                              hipStream_t stream) {
  const float* x  = (const float*)d_in[0];
  const float* Wq = (const float*)d_in[1];
  const float* Wk = (const float*)d_in[2];
  const float* Wv = (const float*)d_in[3];
  const float* Wo = (const float*)d_in[4];
  float* out = (float*)d_out;

  char* ws = (char*)d_ws;
  size_t off = 0;
  auto alloc = [&](size_t bytes) -> void* {
    void* p = ws + off;
    off += (bytes + 255) & ~(size_t)255;
    return p;
  };
  __bf16* xb    = (__bf16*)alloc((size_t)ROWS * D_MODEL * 2);   // x bf16; reused as attn out
  __bf16* QKVb  = (__bf16*)alloc((size_t)ROWS * QKV_LD * 2);
  __bf16* WqkvT = (__bf16*)alloc((size_t)QKV_LD * D_MODEL * 2);
  __bf16* WoT   = (__bf16*)alloc((size_t)D_MODEL * D_MODEL * 2);
  __bf16* Vtb   = (__bf16*)alloc((size_t)BATCH * 64 * VT_LD * 2);

  // Q pre-scale: 1/sqrt(64) * log2(e) folded into Wq (exp2-domain softmax)
  const float SCALE_Q = 0.125f * 1.4426950408889634f;

  k_f32_to_bf16<<<ROWS*D_MODEL/2048, 256, 0, stream>>>(x, xb, ROWS*D_MODEL);
  k_transpose_f32_bf16<<<dim3(D_MODEL/32, D_MODEL/32), 256, 0, stream>>>(Wq, WqkvT, D_MODEL, D_MODEL, SCALE_Q);
  k_transpose_f32_bf16<<<dim3(HEAD_DIM/32, D_MODEL/32), 256, 0, stream>>>(Wk, WqkvT + (size_t)1024*D_MODEL, D_MODEL, HEAD_DIM, 1.0f);
  k_transpose_f32_bf16<<<dim3(HEAD_DIM/32, D_MODEL/32), 256, 0, stream>>>(Wv, WqkvT + (size_t)1088*D_MODEL, D_MODEL, HEAD_DIM, 1.0f);
  k_transpose_f32_bf16<<<dim3(D_MODEL/32, D_MODEL/32), 256, 0, stream>>>(Wo, WoT, D_MODEL, D_MODEL, 1.0f);

  k_gemm<__bf16><<<dim3(ROWS/128, QKV_LD/128), 256, 0, stream>>>(xb, WqkvT, QKVb, ROWS, QKV_LD, D_MODEL);
  k_vt_split<<<dim3(SEQ/64, BATCH), 256, 0, stream>>>(QKVb, Vtb);
  k_attn<<<dim3(SEQ/256, N_HEADS, BATCH), 512, 0, stream>>>(QKVb, Vtb, xb);
  k_gemm<float><<<dim3(ROWS/128, D_MODEL/128), 256, 0, stream>>>(xb, WoT, out, ROWS, D_MODEL, D_MODEL);
}

// Round 11
// 239.058 us; speedup vs baseline: 2.7050x; 1.0229x over previous
//
#include <hip/hip_runtime.h>
#include <hip/hip_bf16.h>

typedef __bf16  bf16x8  __attribute__((ext_vector_type(8)));
typedef __bf16  bf16x4  __attribute__((ext_vector_type(4)));
typedef float   f32x4   __attribute__((ext_vector_type(4)));
typedef unsigned short ushort8 __attribute__((ext_vector_type(8)));

#define D_MODEL 1024
#define HEAD_DIM 64
#define N_HEADS 16
#define BATCH 4
#define SEQ 2048
#define ROWS (BATCH*SEQ)   // 8192
#define QKV_LD 1152        // 1024 (Q) + 64 (K) + 64 (V)
#define VT_LD 2080         // padded: 4160 B rows, breaks 4KB channel aliasing

#define AS1 __attribute__((address_space(1)))
#define AS3 __attribute__((address_space(3)))

// raw v_exp_f32: D = 2^S0 (exp2-domain softmax; scale folded into Wq)
static __device__ inline float exp2_fast(float x) {
  float r; asm("v_exp_f32 %0, %1" : "=v"(r) : "v"(x)); return r;
}

// ---------------- fp32 -> bf16 convert (vectorized) ----------------
__global__ __launch_bounds__(256) void k_f32_to_bf16(const float* __restrict__ in,
                                                     __bf16* __restrict__ out, int n) {
  int i = (blockIdx.x * 256 + threadIdx.x) * 8;
  if (i >= n) return;
  float4 a = *(const float4*)(in + i);
  float4 b = *(const float4*)(in + i + 4);
  __bf16 r[8] __attribute__((aligned(16))) =
      {(__bf16)a.x,(__bf16)a.y,(__bf16)a.z,(__bf16)a.w,
       (__bf16)b.x,(__bf16)b.y,(__bf16)b.z,(__bf16)b.w};
  *(ushort8*)(out + i) = *(const ushort8*)r;
}

// ---------------- transpose + convert + scale: fp32 [R][C] -> bf16 [C][R] ----------------
__global__ __launch_bounds__(256) void k_transpose_f32_bf16(const float* __restrict__ in,
                                                            __bf16* __restrict__ out,
                                                            int R, int C, float scale) {
  __shared__ float t[32][33];
  int tx = threadIdx.x & 31, ty = threadIdx.x >> 5;   // 32x8
  int r0 = blockIdx.y * 32, c0 = blockIdx.x * 32;
  #pragma unroll
  for (int i = 0; i < 4; ++i)
    t[ty + i*8][tx] = in[(size_t)(r0 + ty + i*8) * C + c0 + tx];
  __syncthreads();
  #pragma unroll
  for (int i = 0; i < 4; ++i)
    out[(size_t)(c0 + ty + i*8) * R + r0 + tx] = (__bf16)(t[tx][ty + i*8] * scale);
}

// ---------------- bf16 MFMA GEMM: C[M][N] = A[M][K] * Bt[N][K]^T ----------------
// 128x128 tile, BK=32, 2-phase double-buffered global_load_lds.
template<typename OUT_T>
__global__ __launch_bounds__(256) void k_gemm(const __bf16* __restrict__ A,
                                              const __bf16* __restrict__ Bt,
                                              OUT_T* __restrict__ C,
                                              int M, int N, int K) {
  __shared__ __bf16 As[2][128*32] __attribute__((aligned(16)));
  __shared__ __bf16 Bs[2][128*32] __attribute__((aligned(16)));
  const int tid  = threadIdx.x;
  const int lane = tid & 63, wave = tid >> 6;
  const int wm = wave >> 1, wn = wave & 1;
  const int l15 = lane & 15, lhi = lane >> 4;
  const int arow0 = blockIdx.x * 128;
  const int brow0 = blockIdx.y * 128;
  f32x4 acc[4][4] = {};
  const int srow = lane >> 2;        // 0..15
  const int scol = (lane & 3) * 8;   // 0,8,16,24
  const int nt = K >> 5;

  auto stage = [&](int t, int buf) {
    #pragma unroll
    for (int i = 0; i < 2; ++i) {
      int chunk = i*4 + wave;              // 0..7, 16 rows each
      int r = chunk*16 + srow;
      __builtin_amdgcn_global_load_lds(
          (const AS1 unsigned int*)(A  + (size_t)(arow0 + r)*K + t*32 + scol),
          (AS3 unsigned int*)(&As[buf][0] + chunk*512), 16, 0, 0);
      __builtin_amdgcn_global_load_lds(
          (const AS1 unsigned int*)(Bt + (size_t)(brow0 + r)*K + t*32 + scol),
          (AS3 unsigned int*)(&Bs[buf][0] + chunk*512), 16, 0, 0);
    }
  };

  stage(0, 0);
  asm volatile("s_waitcnt vmcnt(0)" ::: "memory");
  __builtin_amdgcn_s_barrier();

  for (int t = 0; t < nt; ++t) {
    const int cur = t & 1;
    if (t + 1 < nt) stage(t + 1, cur ^ 1);   // prefetch overlaps this tile's compute
    bf16x8 af[4], bfr[4];
    #pragma unroll
    for (int m = 0; m < 4; ++m)
      af[m] = *(const bf16x8*)(&As[cur][0] + (wm*64 + m*16 + l15)*32 + lhi*8);
    #pragma unroll
    for (int n = 0; n < 4; ++n)
      bfr[n] = *(const bf16x8*)(&Bs[cur][0] + (wn*64 + n*16 + l15)*32 + lhi*8);
    #pragma unroll
    for (int m = 0; m < 4; ++m)
      #pragma unroll
      for (int n = 0; n < 4; ++n)
        acc[m][n] = __builtin_amdgcn_mfma_f32_16x16x32_bf16(af[m], bfr[n], acc[m][n], 0, 0, 0);
    asm volatile("s_waitcnt vmcnt(0)" ::: "memory");
    __builtin_amdgcn_s_barrier();
  }
  #pragma unroll
  for (int m = 0; m < 4; ++m)
    #pragma unroll
    for (int n = 0; n < 4; ++n) {
      int row = arow0 + wm*64 + m*16 + lhi*4;
      int col = brow0 + wn*64 + n*16 + l15;
      #pragma unroll
      for (int r = 0; r < 4; ++r)
        C[(size_t)(row + r) * N + col] = (OUT_T)acc[m][n][r];
    }
}

// ---------------- split V cols of QKV -> Vt (transposed, PERMUTED key order) ----------
// Column position within each 64-tile: P(K) = (K&32)|(((K>>2)&3)<<3)|(((K>>4)&1)<<2)|(K&3)
// so PV can consume QK's D-layout scores directly as 16x16x32 A-fragments (no P LDS).
// Inverse (pos -> K): K5=pos5, K4=pos2, K3:2=pos4:3, K1:0=pos1:0.
__global__ __launch_bounds__(256) void k_vt_split(const __bf16* __restrict__ QKV,
                                                  __bf16* __restrict__ Vt) {
  __shared__ __bf16 t[64][72] __attribute__((aligned(16)));
  int st = blockIdx.x, b = blockIdx.y;
  int tid = threadIdx.x;
  int rr = tid >> 3, cc = (tid & 7) * 8;
  #pragma unroll
  for (int i = 0; i < 2; ++i) {
    int s = rr + i*32;
    *(ushort8*)&t[s][cc] =
      *(const ushort8*)(QKV + (size_t)(b*SEQ + st*64 + s) * QKV_LD + 1088 + cc);
  }
  __syncthreads();
  #pragma unroll
  for (int i = 0; i < 2; ++i) {
    int d = rr + i*32;
    __bf16 tmp[8] __attribute__((aligned(16)));
    #pragma unroll
    for (int jj = 0; jj < 8; ++jj) {
      int pos = cc + jj;
      int K = (pos & 3) | (((pos >> 3) & 1) << 2) | (((pos >> 4) & 1) << 3)
            | (((pos >> 2) & 1) << 4) | (pos & 32);
      tmp[jj] = t[K][d];
    }
    *(ushort8*)(Vt + (size_t)(b*64 + d) * VT_LD + st*64 + cc) = *(const ushort8*)tmp;
  }
}

// ---------------- flash attention (MQA), swapped-QK, register-direct PV ----------------
// grid: (SEQ/256, N_HEADS, BATCH), 512 thr. Wave w owns q-rows [w*32, w*32+32).
// QK as mfma(K,Q): s[m][n] holds q=l15, keys n*16+lhi*4+r -> that IS a 16x16x32 A-frag
// under the V column permutation P(K). PV reads V straight from swizzled Vl; no P LDS.
__global__ __launch_bounds__(512, 4) void k_attn(const __bf16* __restrict__ QKV, // [8192][1152]
                                                 const __bf16* __restrict__ Vt,  // [B][64][VT_LD]
                                                 __bf16* __restrict__ O) {       // [8192][1024]
  __shared__ __bf16 Kl[2][64*64];   // 8KB per buf, linear dest for global_load_lds
  __shared__ __bf16 Vl[2][64*64];
  const int qt = blockIdx.x, h = blockIdx.y, b = blockIdx.z;
  const int tid = threadIdx.x, lane = tid & 63, w = tid >> 6;
  const int l15 = lane & 15, lhi = lane >> 4;
  const int l7 = l15 & 7;

  const int srow = lane >> 3;              // 0..7
  const int j8   = lane & 7;               // physical 16B block this lane writes
  const int row_t = w*8 + srow;            // tile row (key for K, d for V)
  const int jsrc = j8 ^ srow;              // inverse-swizzled source block
  const __bf16* Kg = QKV + (size_t)b*SEQ*QKV_LD + 1024;
  const __bf16* Vg = Vt  + (size_t)b*64*VT_LD;

  auto stage = [&](int t, int buf) {
    __builtin_amdgcn_global_load_lds(
        (const AS1 unsigned int*)(Kg + (size_t)(t*64 + row_t)*QKV_LD + jsrc*8),
        (AS3 unsigned int*)(&Kl[buf][0] + w*512), 16, 0, 0);
    __builtin_amdgcn_global_load_lds(
        (const AS1 unsigned int*)(Vg + (size_t)row_t*VT_LD + t*64 + jsrc*8),
        (AS3 unsigned int*)(&Vl[buf][0] + w*512), 16, 0, 0);
  };

  stage(0, 0);

  // Q fragments (2 m-tiles x 2 dim-halves); MFMA B-operand (col=q=l15, k=dim lhi*8+j)
  bf16x8 aq[2][2];
  {
    const __bf16* qp = QKV + (size_t)(b*SEQ + qt*256 + w*32 + l15)*QKV_LD + h*HEAD_DIM;
    aq[0][0] = *(const bf16x8*)(qp +               lhi*8);
    aq[0][1] = *(const bf16x8*)(qp +          32 + lhi*8);
    aq[1][0] = *(const bf16x8*)(qp + 16*QKV_LD +      lhi*8);
    aq[1][1] = *(const bf16x8*)(qp + 16*QKV_LD + 32 + lhi*8);
  }

  f32x4 oacc[2][4] = {};
  float mrun[2] = {-__builtin_inff(), -__builtin_inff()};
  float lrun[2] = {0.f, 0.f};

  asm volatile("s_waitcnt vmcnt(0)" ::: "memory");
  __builtin_amdgcn_s_barrier();

  for (int t = 0; t < SEQ/64; ++t) {
    const int cur = t & 1;
    if (t < SEQ/64 - 1) {
      stage(t+1, cur^1);                                   // prefetch stays in flight
      asm volatile("s_waitcnt vmcnt(2)" ::: "memory");     // tile t complete
    } else {
      asm volatile("s_waitcnt vmcnt(0)" ::: "memory");
    }
    const char* Kc = (const char*)&Kl[cur][0];
    const char* Vc = (const char*)&Vl[cur][0];

    // ---- QK^T (swapped): s[m][n] = K(n-block) x Q(m-tile); lane: q=l15, keys lhi*4+r ----
    f32x4 s[2][4] = {};
    __builtin_amdgcn_s_setprio(1);
    #pragma unroll
    for (int n = 0; n < 4; ++n) {
      const int key = n*16 + l15;
      bf16x8 kb0 = *(const bf16x8*)(Kc + key*128 + (((    lhi) ^ l7)*16));
      bf16x8 kb1 = *(const bf16x8*)(Kc + key*128 + (((4 + lhi) ^ l7)*16));
      #pragma unroll
      for (int m = 0; m < 2; ++m) {
        s[m][n] = __builtin_amdgcn_mfma_f32_16x16x32_bf16(kb0, aq[m][0], s[m][n], 0, 0, 0);
        s[m][n] = __builtin_amdgcn_mfma_f32_16x16x32_bf16(kb1, aq[m][1], s[m][n], 0, 0, 0);
      }
    }
    __builtin_amdgcn_s_setprio(0);

    // ---- row max: in-lane 16 keys, then xor-16/32 across the 4 sibling lanes ----
    float tm[2];
    #pragma unroll
    for (int m = 0; m < 2; ++m) {
      float a0 = fmaxf(fmaxf(s[m][0][0], s[m][0][1]), fmaxf(s[m][0][2], s[m][0][3]));
      float a1 = fmaxf(fmaxf(s[m][1][0], s[m][1][1]), fmaxf(s[m][1][2], s[m][1][3]));
      float a2 = fmaxf(fmaxf(s[m][2][0], s[m][2][1]), fmaxf(s[m][2][2], s[m][2][3]));
      float a3 = fmaxf(fmaxf(s[m][3][0], s[m][3][1]), fmaxf(s[m][3][2], s[m][3][3]));
      tm[m] = fmaxf(fmaxf(a0, a1), fmaxf(a2, a3));
      tm[m] = fmaxf(tm[m], __shfl_xor(tm[m], 16, 64));
      tm[m] = fmaxf(tm[m], __shfl_xor(tm[m], 32, 64));
    }

    // ---- defer-max (T13): rescale only when max grows past THR=8 (log2 units, P<=256) ----
    int nogrow = (tm[0] <= mrun[0] + 8.f) && (tm[1] <= mrun[1] + 8.f);
    if (!__all(nogrow)) {
      float corr[2];
      #pragma unroll
      for (int m = 0; m < 2; ++m) {
        float mnew = fmaxf(mrun[m], tm[m]);
        corr[m] = exp2_fast(mrun[m] - mnew);
        mrun[m] = mnew;
        lrun[m] *= corr[m];
      }
      #pragma unroll
      for (int m = 0; m < 2; ++m) {
        float cb[4];
        #pragma unroll
        for (int r = 0; r < 4; ++r) cb[r] = __shfl(corr[m], lhi*4 + r, 64);
        #pragma unroll
        for (int n = 0; n < 4; ++n)
          #pragma unroll
          for (int r = 0; r < 4; ++r)
            oacc[m][n][r] *= cb[r];
      }
    }

    // ---- P = 2^(s-m) packed DIRECTLY into PV A-fragments (no LDS round-trip) ----
    // pa[m][c] (c = key-half) element (n&1)*4+r <- key (2c+(n&1))*16 + lhi*4 + r
    bf16x8 pa[2][2];
    #pragma unroll
    for (int m = 0; m < 2; ++m)
      #pragma unroll
      for (int n = 0; n < 4; ++n)
        #pragma unroll
        for (int r = 0; r < 4; ++r) {
          float pv = exp2_fast(s[m][n][r] - mrun[m]);
          lrun[m] += pv;
          pa[m][n >> 1][(n & 1)*4 + r] = (__bf16)pv;
        }

    // ---- PV: V columns pre-permuted so vb IS the matching B-fragment ----
    __builtin_amdgcn_s_setprio(1);
    #pragma unroll
    for (int dblk = 0; dblk < 4; ++dblk) {
      const int d = dblk*16 + l15;
      bf16x8 vb0 = *(const bf16x8*)(Vc + d*128 + (((    lhi) ^ l7)*16));   // key-half 0
      bf16x8 vb1 = *(const bf16x8*)(Vc + d*128 + (((4 + lhi) ^ l7)*16));   // key-half 1
      #pragma unroll
      for (int m = 0; m < 2; ++m) {
        oacc[m][dblk] = __builtin_amdgcn_mfma_f32_16x16x32_bf16(pa[m][0], vb0, oacc[m][dblk], 0, 0, 0);
        oacc[m][dblk] = __builtin_amdgcn_mfma_f32_16x16x32_bf16(pa[m][1], vb1, oacc[m][dblk], 0, 0, 0);
      }
    }
    __builtin_amdgcn_s_setprio(0);
    __builtin_amdgcn_s_barrier();   // all waves done reading bufs before next overwrite
  }

  // ---- reduce l across the 4 sibling lanes, broadcast to oacc rows, write ----
  #pragma unroll
  for (int m = 0; m < 2; ++m) {
    lrun[m] += __shfl_xor(lrun[m], 16, 64);
    lrun[m] += __shfl_xor(lrun[m], 32, 64);
  }
  float rinv[2][4];
  #pragma unroll
  for (int m = 0; m < 2; ++m)
    #pragma unroll
    for (int r = 0; r < 4; ++r)
      rinv[m][r] = __builtin_amdgcn_rcpf(__shfl(lrun[m], lhi*4 + r, 64));
  #pragma unroll
  for (int m = 0; m < 2; ++m)
    #pragma unroll
    for (int n = 0; n < 4; ++n)
      #pragma unroll
      for (int r = 0; r < 4; ++r) {
        size_t row = (size_t)b*SEQ + qt*256 + w*32 + m*16 + lhi*4 + r;
        O[row * D_MODEL + h*HEAD_DIM + n*16 + l15] = (__bf16)(oacc[m][n][r] * rinv[m][r]);
      }
}

extern "C" void kernel_launch(void* const* d_in, const int* in_sizes, int n_in,
                              void* d_out, int out_size, void* d_ws, size_t ws_size,
                              hipStream_t stream) {
  const float* x  = (const float*)d_in[0];
  const float* Wq = (const float*)d_in[1];
  const float* Wk = (const float*)d_in[2];
  const float* Wv = (const float*)d_in[3];
  const float* Wo = (const float*)d_in[4];
  float* out = (float*)d_out;

  char* ws = (char*)d_ws;
  size_t off = 0;
  auto alloc = [&](size_t bytes) -> void* {
    void* p = ws + off;
    off += (bytes + 255) & ~(size_t)255;
    return p;
  };
  __bf16* xb    = (__bf16*)alloc((size_t)ROWS * D_MODEL * 2);   // x bf16; reused as attn out
  __bf16* QKVb  = (__bf16*)alloc((size_t)ROWS * QKV_LD * 2);
  __bf16* WqkvT = (__bf16*)alloc((size_t)QKV_LD * D_MODEL * 2);
  __bf16* WoT   = (__bf16*)alloc((size_t)D_MODEL * D_MODEL * 2);
  __bf16* Vtb   = (__bf16*)alloc((size_t)BATCH * 64 * VT_LD * 2);

  // Q pre-scale: 1/sqrt(64) * log2(e) folded into Wq (exp2-domain softmax)
  const float SCALE_Q = 0.125f * 1.4426950408889634f;

  k_f32_to_bf16<<<ROWS*D_MODEL/2048, 256, 0, stream>>>(x, xb, ROWS*D_MODEL);
  k_transpose_f32_bf16<<<dim3(D_MODEL/32, D_MODEL/32), 256, 0, stream>>>(Wq, WqkvT, D_MODEL, D_MODEL, SCALE_Q);
  k_transpose_f32_bf16<<<dim3(HEAD_DIM/32, D_MODEL/32), 256, 0, stream>>>(Wk, WqkvT + (size_t)1024*D_MODEL, D_MODEL, HEAD_DIM, 1.0f);
  k_transpose_f32_bf16<<<dim3(HEAD_DIM/32, D_MODEL/32), 256, 0, stream>>>(Wv, WqkvT + (size_t)1088*D_MODEL, D_MODEL, HEAD_DIM, 1.0f);
  k_transpose_f32_bf16<<<dim3(D_MODEL/32, D_MODEL/32), 256, 0, stream>>>(Wo, WoT, D_MODEL, D_MODEL, 1.0f);

  k_gemm<__bf16><<<dim3(ROWS/128, QKV_LD/128), 256, 0, stream>>>(xb, WqkvT, QKVb, ROWS, QKV_LD, D_MODEL);
  k_vt_split<<<dim3(SEQ/64, BATCH), 256, 0, stream>>>(QKVb, Vtb);
  k_attn<<<dim3(SEQ/256, N_HEADS, BATCH), 512, 0, stream>>>(QKVb, Vtb, xb);
  k_gemm<float><<<dim3(ROWS/128, D_MODEL/128), 256, 0, stream>>>(xb, WoT, out, ROWS, D_MODEL, D_MODEL);
}